// Round 1
// baseline (392.652 us; speedup 1.0000x reference)
//
#include <hip/hip_runtime.h>
#include <stdint.h>

typedef unsigned short u16;
typedef __attribute__((ext_vector_type(8))) short bf16x8;
typedef __attribute__((ext_vector_type(4))) float f32x4;
typedef __attribute__((address_space(1))) unsigned int as1u;
typedef __attribute__((address_space(3))) unsigned int as3u;

#define DEV __device__ __forceinline__

DEV u16 f2bf(float f) {
  union { float f; unsigned u; } v; v.f = f;
  unsigned r = v.u + 0x7FFFu + ((v.u >> 16) & 1u);  // RNE
  return (u16)(r >> 16);
}

DEV void gl_lds16(const void* g, void* l) {
  __builtin_amdgcn_global_load_lds(
      reinterpret_cast<as1u*>(reinterpret_cast<uintptr_t>(g)),
      reinterpret_cast<as3u*>(reinterpret_cast<uintptr_t>(l)), 16, 0, 0);
}

// ---------------- weight transpose+convert:  Wt[n][k] = bf16(W[k][n]) ------
__global__ __launch_bounds__(256) void wtrans_k(const float* __restrict__ W,
                                                u16* __restrict__ Wt) {
  __shared__ float t[64][65];
  const int tid = threadIdx.x;
  const int n0 = blockIdx.x * 64, k0 = blockIdx.y * 64;
  const int c = tid & 63, r4 = tid >> 6;
#pragma unroll
  for (int i = 0; i < 16; ++i) {
    int r = r4 * 16 + i;
    t[r][c] = W[(size_t)(k0 + r) * 1024 + n0 + c];
  }
  __syncthreads();
#pragma unroll
  for (int i = 0; i < 16; ++i) {
    int r = r4 * 16 + i;
    Wt[(size_t)(n0 + r) * 1024 + k0 + c] = f2bf(t[c][r]);
  }
}

// ---------------- GEMM: C = (A @ Wt^T + bias) * scale ----------------------
// A: M x 1024 (fp32 if AF32 else bf16, row-major).  Bt: bf16 [N=1024][K=1024].
// OMODE 0: bf16 out, head-major [b][h][l][dh]
// OMODE 1: bf16 out, V-transposed [b][h][dh][l]
// OMODE 2: fp32 out, linear [m][n]
template <bool AF32, int OMODE>
__global__ __launch_bounds__(256) void gemm_k(const void* __restrict__ Ap,
                                              const u16* __restrict__ Bt,
                                              const float* __restrict__ bias,
                                              void* __restrict__ Cp,
                                              float scale) {
  constexpr int K = 1024;
  __shared__ alignas(16) char smem[AF32 ? 49152 : 32768];
  float* Asf = (float*)smem;
  u16* Ash = (u16*)smem;
  u16* Bs = (u16*)(smem + (AF32 ? 32768 : 16384));

  const int tid = threadIdx.x;
  const int lane = tid & 63, wid = tid >> 6;
  const int brow = (blockIdx.x >> 3) * 128;
  const int bcol = (blockIdx.x & 7) * 128;
  const int wr = (wid >> 1) * 64, wc = (wid & 1) * 64;

  const float* Af = (const float*)Ap;
  const u16* Ah = (const u16*)Ap;

  f32x4 acc[4][4] = {};

  for (int kt = 0; kt < K; kt += 64) {
    __syncthreads();
    if constexpr (AF32) {
#pragma unroll
      for (int i = 0; i < 8; ++i) {
        int row = i * 16 + (tid >> 4);
        gl_lds16(Af + (size_t)(brow + row) * K + kt + ((tid & 15) << 2),
                 smem + i * 4096 + wid * 1024);
      }
    } else {
#pragma unroll
      for (int i = 0; i < 4; ++i) {
        int row = i * 32 + (tid >> 3);
        gl_lds16(Ah + (size_t)(brow + row) * K + kt + ((tid & 7) << 3),
                 smem + i * 4096 + wid * 1024);
      }
    }
#pragma unroll
    for (int i = 0; i < 4; ++i) {
      int row = i * 32 + (tid >> 3);
      gl_lds16(Bt + (size_t)(bcol + row) * K + kt + ((tid & 7) << 3),
               (char*)Bs + i * 4096 + wid * 1024);
    }
    __syncthreads();

#pragma unroll
    for (int kk = 0; kk < 2; ++kk) {
      const int kcol = kk * 32 + (lane >> 4) * 8;
      bf16x8 a[4], bfr[4];
#pragma unroll
      for (int m = 0; m < 4; ++m) {
        if constexpr (AF32) {
          const float* p = Asf + (wr + m * 16 + (lane & 15)) * 64 + kcol;
          float4 x0 = *(const float4*)p;
          float4 x1 = *(const float4*)(p + 4);
          bf16x8 t;
          t[0] = (short)f2bf(x0.x); t[1] = (short)f2bf(x0.y);
          t[2] = (short)f2bf(x0.z); t[3] = (short)f2bf(x0.w);
          t[4] = (short)f2bf(x1.x); t[5] = (short)f2bf(x1.y);
          t[6] = (short)f2bf(x1.z); t[7] = (short)f2bf(x1.w);
          a[m] = t;
        } else {
          a[m] = *(const bf16x8*)(Ash + (wr + m * 16 + (lane & 15)) * 64 + kcol);
        }
      }
#pragma unroll
      for (int n = 0; n < 4; ++n)
        bfr[n] = *(const bf16x8*)(Bs + (wc + n * 16 + (lane & 15)) * 64 + kcol);
#pragma unroll
      for (int m = 0; m < 4; ++m)
#pragma unroll
        for (int n = 0; n < 4; ++n)
          acc[m][n] = __builtin_amdgcn_mfma_f32_16x16x32_bf16(
              a[m], bfr[n], acc[m][n], 0, 0, 0);
    }
  }

#pragma unroll
  for (int m = 0; m < 4; ++m) {
    const int row0 = brow + wr + m * 16 + ((lane >> 4) << 2);
#pragma unroll
    for (int n = 0; n < 4; ++n) {
      const int col = bcol + wc + n * 16 + (lane & 15);
      const float bv = bias[col];
#pragma unroll
      for (int r = 0; r < 4; ++r) {
        const int row = row0 + r;
        const float val = (acc[m][n][r] + bv) * scale;
        if constexpr (OMODE == 0) {
          const int b = row >> 11, l = row & 2047, h = col >> 6, dh = col & 63;
          ((u16*)Cp)[((size_t)((b << 4) + h) * 2048 + l) * 64 + dh] = f2bf(val);
        } else if constexpr (OMODE == 1) {
          const int b = row >> 11, l = row & 2047, h = col >> 6, dh = col & 63;
          ((u16*)Cp)[((size_t)((b << 4) + h) * 64 + dh) * 2048 + l] = f2bf(val);
        } else {
          ((float*)Cp)[(size_t)row * 1024 + col] = val;
        }
      }
    }
  }
}

// ---------------- flash attention, causal --------------------------------
// Q,K: bf16 [bh][l][64]; Vt: bf16 [bh][64][l]; ctx: bf16 [b][l][1024]
__global__ __launch_bounds__(256) void attn_k(const u16* __restrict__ Q,
                                              const u16* __restrict__ K,
                                              const u16* __restrict__ Vt,
                                              u16* __restrict__ ctx,
                                              float2* __restrict__ stats) {
  const int tid = threadIdx.x, lane = tid & 63, wid = tid >> 6;
  const int bh = blockIdx.x, qt = blockIdx.y;
  const int b = bh >> 4, h = bh & 15;
  const size_t base = (size_t)bh * 2048 * 64;

  __shared__ alignas(16) u16 Qs[4096], Ks[4096], Vs[4096], Ps[4096];

  {
    const u16* g = Q + base + (size_t)qt * 4096;
#pragma unroll
    for (int i = 0; i < 2; ++i)
      gl_lds16(g + i * 2048 + tid * 8, (char*)Qs + i * 4096 + wid * 1024);
  }

  f32x4 acc_o[4] = {};
  float m_run[4] = {-1e30f, -1e30f, -1e30f, -1e30f};
  float l_run[4] = {0.f, 0.f, 0.f, 0.f};
  const int qrow0 = qt * 64 + wid * 16 + ((lane >> 4) << 2);

  for (int kt = 0; kt <= qt; ++kt) {
    __syncthreads();
    {
      const u16* kg = K + base + (size_t)kt * 4096;
#pragma unroll
      for (int i = 0; i < 2; ++i)
        gl_lds16(kg + i * 2048 + tid * 8, (char*)Ks + i * 4096 + wid * 1024);
      const u16* vg = Vt + base + (size_t)(tid >> 3) * 2048 + kt * 64 + (tid & 7) * 8;
#pragma unroll
      for (int i = 0; i < 2; ++i)
        gl_lds16(vg + (size_t)i * 32 * 2048, (char*)Vs + i * 4096 + wid * 1024);
    }
    __syncthreads();

    f32x4 s[4] = {};
#pragma unroll
    for (int kk = 0; kk < 2; ++kk) {
      const int kc = kk * 32 + (lane >> 4) * 8;
      bf16x8 aq = *(const bf16x8*)(Qs + (wid * 16 + (lane & 15)) * 64 + kc);
#pragma unroll
      for (int n = 0; n < 4; ++n) {
        bf16x8 bk = *(const bf16x8*)(Ks + (n * 16 + (lane & 15)) * 64 + kc);
        s[n] = __builtin_amdgcn_mfma_f32_16x16x32_bf16(aq, bk, s[n], 0, 0, 0);
      }
    }

    const int kb = kt * 64;
    const bool diag = (kt == qt);
#pragma unroll
    for (int r = 0; r < 4; ++r) {
      const int q = qrow0 + r;
      if (diag) {
#pragma unroll
        for (int n = 0; n < 4; ++n)
          if (kb + n * 16 + (lane & 15) > q) s[n][r] = -1e30f;
      }
      float mx = fmaxf(fmaxf(s[0][r], s[1][r]), fmaxf(s[2][r], s[3][r]));
#pragma unroll
      for (int off = 1; off < 16; off <<= 1)
        mx = fmaxf(mx, __shfl_xor(mx, off, 64));
      const float mn = fmaxf(m_run[r], mx);
      const float alpha = __expf(m_run[r] - mn);
      float rs = 0.f;
#pragma unroll
      for (int n = 0; n < 4; ++n) {
        const float p = __expf(s[n][r] - mn);
        s[n][r] = p;
        rs += p;
      }
#pragma unroll
      for (int off = 1; off < 16; off <<= 1) rs += __shfl_xor(rs, off, 64);
      m_run[r] = mn;
      l_run[r] = l_run[r] * alpha + rs;
#pragma unroll
      for (int n = 0; n < 4; ++n) {
        acc_o[n][r] *= alpha;
        Ps[(wid * 16 + (lane >> 4) * 4 + r) * 64 + n * 16 + (lane & 15)] =
            f2bf(s[n][r]);
      }
    }
    asm volatile("s_waitcnt lgkmcnt(0)" ::: "memory");

#pragma unroll
    for (int kk = 0; kk < 2; ++kk) {
      const int kc = kk * 32 + (lane >> 4) * 8;
      bf16x8 pf = *(const bf16x8*)(Ps + (wid * 16 + (lane & 15)) * 64 + kc);
#pragma unroll
      for (int n = 0; n < 4; ++n) {
        bf16x8 vf = *(const bf16x8*)(Vs + (n * 16 + (lane & 15)) * 64 + kc);
        acc_o[n] = __builtin_amdgcn_mfma_f32_16x16x32_bf16(pf, vf, acc_o[n], 0, 0, 0);
      }
    }
  }

#pragma unroll
  for (int r = 0; r < 4; ++r) {
    const int q = qrow0 + r;
    const float rl = 1.0f / l_run[r];
#pragma unroll
    for (int n = 0; n < 4; ++n) {
      const int dh = n * 16 + (lane & 15);
      ctx[((size_t)(b * 2048 + q)) * 1024 + h * 64 + dh] = f2bf(acc_o[n][r] * rl);
    }
    if (h == 0 && (lane & 15) == 0)
      stats[b * 2048 + q] = make_float2(m_run[r], l_run[r]);
  }
}

// ---------------- top_attn (head 0) probabilities -------------------------
__global__ __launch_bounds__(256) void probs_k(const u16* __restrict__ Q,
                                               const u16* __restrict__ K,
                                               const float2* __restrict__ stats,
                                               float* __restrict__ out) {
  const int tid = threadIdx.x, lane = tid & 63, wid = tid >> 6;
  const int kt2 = blockIdx.x, qt = blockIdx.y, b = blockIdx.z;
  const int q0 = qt * 64, c0 = kt2 * 128;
  float* ot = out + ((size_t)b * 2048 + q0) * 2048 + c0;

  if (c0 > q0 + 63) {  // whole tile masked -> zero-fill
    const float4 z = make_float4(0.f, 0.f, 0.f, 0.f);
#pragma unroll
    for (int i = 0; i < 8; ++i) {
      const int idx = i * 256 + tid;
      *(float4*)(ot + (size_t)(idx >> 5) * 2048 + ((idx & 31) << 2)) = z;
    }
    return;
  }

  __shared__ alignas(16) u16 Qs[4096], Ks2[8192];
  const size_t base = (size_t)(b * 16) * 2048 * 64;  // h = 0
  const u16* qg = Q + base + (size_t)q0 * 64;
#pragma unroll
  for (int i = 0; i < 2; ++i)
    gl_lds16(qg + i * 2048 + tid * 8, (char*)Qs + i * 4096 + wid * 1024);
  const u16* kg = K + base + (size_t)c0 * 64;
#pragma unroll
  for (int i = 0; i < 4; ++i)
    gl_lds16(kg + i * 2048 + tid * 8, (char*)Ks2 + i * 4096 + wid * 1024);
  __syncthreads();

  f32x4 s[8] = {};
#pragma unroll
  for (int kk = 0; kk < 2; ++kk) {
    const int kc = kk * 32 + (lane >> 4) * 8;
    bf16x8 aq = *(const bf16x8*)(Qs + (wid * 16 + (lane & 15)) * 64 + kc);
#pragma unroll
    for (int n = 0; n < 8; ++n) {
      bf16x8 bk = *(const bf16x8*)(Ks2 + (n * 16 + (lane & 15)) * 64 + kc);
      s[n] = __builtin_amdgcn_mfma_f32_16x16x32_bf16(aq, bk, s[n], 0, 0, 0);
    }
  }

#pragma unroll
  for (int r = 0; r < 4; ++r) {
    const int q = q0 + wid * 16 + ((lane >> 4) << 2) + r;
    const float2 st = stats[b * 2048 + q];
    const float rl = 1.0f / st.y;
#pragma unroll
    for (int n = 0; n < 8; ++n) {
      const int kp = c0 + n * 16 + (lane & 15);
      out[((size_t)b * 2048 + q) * 2048 + kp] =
          (kp <= q) ? __expf(s[n][r] - st.x) * rl : 0.f;
    }
  }
}

extern "C" void kernel_launch(void* const* d_in, const int* in_sizes, int n_in,
                              void* d_out, int out_size, void* d_ws,
                              size_t ws_size, hipStream_t stream) {
  (void)in_sizes; (void)n_in; (void)out_size; (void)ws_size;
  const float* key = (const float*)d_in[0];
  const float* value = (const float*)d_in[1];
  const float* query = (const float*)d_in[2];
  // d_in[3] = mask (causal triu k=1) -- implemented analytically
  const float* Wk = (const float*)d_in[4];
  const float* bk = (const float*)d_in[5];
  const float* Wv = (const float*)d_in[6];
  const float* bv = (const float*)d_in[7];
  const float* Wq = (const float*)d_in[8];
  const float* bq = (const float*)d_in[9];
  const float* Wo = (const float*)d_in[10];
  const float* bo = (const float*)d_in[11];

  char* ws = (char*)d_ws;  // needs ~75.6 MB
  u16* WtK = (u16*)(ws);
  u16* WtV = (u16*)(ws + (2u << 20));
  u16* WtQ = (u16*)(ws + (4u << 20));
  u16* WtO = (u16*)(ws + (6u << 20));
  u16* Kup = (u16*)(ws + (8u << 20));   // [b][h][l][dh] bf16, 16 MB
  u16* Qup = (u16*)(ws + (24u << 20));  // [b][h][l][dh] bf16, 16 MB
  u16* Vt  = (u16*)(ws + (40u << 20));  // [b][h][dh][l] bf16, 16 MB
  u16* ctx = (u16*)(ws + (56u << 20));  // [b][l][1024] bf16, 16 MB
  float2* stats = (float2*)(ws + (72u << 20));  // [b*2048] (m, lsum)

  dim3 tg(16, 16);
  wtrans_k<<<tg, 256, 0, stream>>>(Wk, WtK);
  wtrans_k<<<tg, 256, 0, stream>>>(Wv, WtV);
  wtrans_k<<<tg, 256, 0, stream>>>(Wq, WtQ);
  wtrans_k<<<tg, 256, 0, stream>>>(Wo, WtO);

  gemm_k<true, 0><<<512, 256, 0, stream>>>(key, WtK, bk, Kup, 1.0f);
  gemm_k<true, 1><<<512, 256, 0, stream>>>(value, WtV, bv, Vt, 1.0f);
  gemm_k<true, 0><<<512, 256, 0, stream>>>(query, WtQ, bq, Qup, 0.125f);

  attn_k<<<dim3(64, 32), 256, 0, stream>>>(Qup, Kup, Vt, ctx, stats);

  float* out = (float*)d_out;
  probs_k<<<dim3(16, 32, 4), 256, 0, stream>>>(Qup, Kup, stats,
                                               out + (size_t)8388608);

  gemm_k<false, 2><<<512, 256, 0, stream>>>(ctx, WtO, bo, out, 1.0f);
}

// Round 2
// 353.669 us; speedup vs baseline: 1.1102x; 1.1102x over previous
//
#include <hip/hip_runtime.h>
#include <stdint.h>

typedef unsigned short u16;
typedef __attribute__((ext_vector_type(8))) short bf16x8;
typedef __attribute__((ext_vector_type(4))) float f32x4;
typedef __attribute__((address_space(1))) unsigned int as1u;
typedef __attribute__((address_space(3))) unsigned int as3u;

#define DEV __device__ __forceinline__

DEV u16 f2bf(float f) {
  union { float f; unsigned u; } v; v.f = f;
  unsigned r = v.u + 0x7FFFu + ((v.u >> 16) & 1u);  // RNE
  return (u16)(r >> 16);
}

DEV void gl_lds16(const void* g, void* l) {
  __builtin_amdgcn_global_load_lds(
      reinterpret_cast<as1u*>(reinterpret_cast<uintptr_t>(g)),
      reinterpret_cast<as3u*>(reinterpret_cast<uintptr_t>(l)), 16, 0, 0);
}

// XOR-swizzled index helpers (T2 analog). Tiles are [rows][64] elements.
// bf16 tile (128B rows): u16 index.  fp32 tile (256B rows): float index.
DEV int swzh(int r, int c) { return r * 64 + (c ^ ((r & 7) << 3)); }
DEV int swzf(int r, int c) { return r * 64 + (c ^ ((r & 7) << 2)); }

// ---------------- weight transpose+convert:  Wt[n][k] = bf16(W[k][n]) ------
__global__ __launch_bounds__(256) void wtrans_k(const float* __restrict__ W,
                                                u16* __restrict__ Wt) {
  __shared__ float t[64][65];
  const int tid = threadIdx.x;
  const int n0 = blockIdx.x * 64, k0 = blockIdx.y * 64;
  const int c = tid & 63, r4 = tid >> 6;
#pragma unroll
  for (int i = 0; i < 16; ++i) {
    int r = r4 * 16 + i;
    t[r][c] = W[(size_t)(k0 + r) * 1024 + n0 + c];
  }
  __syncthreads();
#pragma unroll
  for (int i = 0; i < 16; ++i) {
    int r = r4 * 16 + i;
    Wt[(size_t)(n0 + r) * 1024 + k0 + c] = f2bf(t[c][r]);
  }
}

// ---------------- GEMM: C = (A @ Wt^T + bias) * scale ----------------------
// A: M x 1024 (fp32 if AF32 else bf16, row-major).  Bt: bf16 [N=1024][K=1024].
// OMODE 0: bf16 out, head-major [b][h][l][dh]
// OMODE 1: bf16 out, V-transposed [b][h][dh][l]
// OMODE 2: fp32 out, linear [m][n]
template <bool AF32, int OMODE>
__global__ __launch_bounds__(256) void gemm_k(const void* __restrict__ Ap,
                                              const u16* __restrict__ Bt,
                                              const float* __restrict__ bias,
                                              void* __restrict__ Cp,
                                              float scale) {
  constexpr int K = 1024;
  __shared__ alignas(16) char smem[AF32 ? 49152 : 32768];
  float* Asf = (float*)smem;
  u16* Ash = (u16*)smem;
  u16* Bs = (u16*)(smem + (AF32 ? 32768 : 16384));

  const int tid = threadIdx.x;
  const int lane = tid & 63, wid = tid >> 6;
  const int brow = (blockIdx.x >> 3) * 128;
  const int bcol = (blockIdx.x & 7) * 128;
  const int wr = (wid >> 1) * 64, wc = (wid & 1) * 64;

  const float* Af = (const float*)Ap;
  const u16* Ah = (const u16*)Ap;

  f32x4 acc[4][4] = {};

  for (int kt = 0; kt < K; kt += 64) {
    __syncthreads();
    if constexpr (AF32) {
#pragma unroll
      for (int i = 0; i < 8; ++i) {
        int row = i * 16 + (tid >> 4);  // LDS row; dest linear, src pre-swizzled
        gl_lds16(Af + (size_t)(brow + row) * K + kt +
                     (((tid & 15) ^ (row & 7)) << 2),
                 smem + i * 4096 + wid * 1024);
      }
    } else {
#pragma unroll
      for (int i = 0; i < 4; ++i) {
        int row = i * 32 + (tid >> 3);
        gl_lds16(Ah + (size_t)(brow + row) * K + kt +
                     (((tid & 7) ^ (row & 7)) << 3),
                 smem + i * 4096 + wid * 1024);
      }
    }
#pragma unroll
    for (int i = 0; i < 4; ++i) {
      int row = i * 32 + (tid >> 3);
      gl_lds16(Bt + (size_t)(bcol + row) * K + kt +
                   (((tid & 7) ^ (row & 7)) << 3),
               (char*)Bs + i * 4096 + wid * 1024);
    }
    __syncthreads();

#pragma unroll
    for (int kk = 0; kk < 2; ++kk) {
      const int kcol = kk * 32 + (lane >> 4) * 8;
      bf16x8 a[4], bfr[4];
#pragma unroll
      for (int m = 0; m < 4; ++m) {
        const int row = wr + m * 16 + (lane & 15);
        if constexpr (AF32) {
          float4 x0 = *(const float4*)(Asf + swzf(row, kcol));
          float4 x1 = *(const float4*)(Asf + swzf(row, kcol + 4));
          bf16x8 t;
          t[0] = (short)f2bf(x0.x); t[1] = (short)f2bf(x0.y);
          t[2] = (short)f2bf(x0.z); t[3] = (short)f2bf(x0.w);
          t[4] = (short)f2bf(x1.x); t[5] = (short)f2bf(x1.y);
          t[6] = (short)f2bf(x1.z); t[7] = (short)f2bf(x1.w);
          a[m] = t;
        } else {
          a[m] = *(const bf16x8*)(Ash + swzh(row, kcol));
        }
      }
#pragma unroll
      for (int n = 0; n < 4; ++n)
        bfr[n] = *(const bf16x8*)(Bs + swzh(wc + n * 16 + (lane & 15), kcol));
#pragma unroll
      for (int m = 0; m < 4; ++m)
#pragma unroll
        for (int n = 0; n < 4; ++n)
          acc[m][n] = __builtin_amdgcn_mfma_f32_16x16x32_bf16(
              a[m], bfr[n], acc[m][n], 0, 0, 0);
    }
  }

#pragma unroll
  for (int m = 0; m < 4; ++m) {
    const int row0 = brow + wr + m * 16 + ((lane >> 4) << 2);
#pragma unroll
    for (int n = 0; n < 4; ++n) {
      const int col = bcol + wc + n * 16 + (lane & 15);
      const float bv = bias[col];
#pragma unroll
      for (int r = 0; r < 4; ++r) {
        const int row = row0 + r;
        const float val = (acc[m][n][r] + bv) * scale;
        if constexpr (OMODE == 0) {
          const int b = row >> 11, l = row & 2047, h = col >> 6, dh = col & 63;
          ((u16*)Cp)[((size_t)((b << 4) + h) * 2048 + l) * 64 + dh] = f2bf(val);
        } else if constexpr (OMODE == 1) {
          const int b = row >> 11, l = row & 2047, h = col >> 6, dh = col & 63;
          ((u16*)Cp)[((size_t)((b << 4) + h) * 64 + dh) * 2048 + l] = f2bf(val);
        } else {
          ((float*)Cp)[(size_t)row * 1024 + col] = val;
        }
      }
    }
  }
}

// ---------------- flash attention, causal --------------------------------
// Q,K: bf16 [bh][l][64] (Q pre-scaled by 0.125*log2e); Vt: bf16 [bh][64][l]
// Softmax runs in the log2 domain (exp2). stats = (m_log2, lsum) for head 0.
__global__ __launch_bounds__(256) void attn_k(const u16* __restrict__ Q,
                                              const u16* __restrict__ K,
                                              const u16* __restrict__ Vt,
                                              u16* __restrict__ ctx,
                                              float2* __restrict__ stats) {
  const int tid = threadIdx.x, lane = tid & 63, wid = tid >> 6;
  const int bh = blockIdx.x, qt = blockIdx.y;
  const int b = bh >> 4, h = bh & 15;
  const size_t base = (size_t)bh * 2048 * 64;

  __shared__ alignas(16) u16 Qs[4096], Ks[4096], Vs[4096], Ps[4096];

  // stage Q (linear dest, pre-swizzled source column)
#pragma unroll
  for (int i = 0; i < 2; ++i) {
    int row = i * 32 + (tid >> 3);
    gl_lds16(Q + base + (size_t)(qt * 64 + row) * 64 +
                 (((tid & 7) ^ (row & 7)) << 3),
             (char*)Qs + i * 4096 + wid * 1024);
  }
  __syncthreads();
  bf16x8 qf[2];
#pragma unroll
  for (int kk = 0; kk < 2; ++kk)
    qf[kk] = *(const bf16x8*)(Qs + swzh(wid * 16 + (lane & 15),
                                        kk * 32 + (lane >> 4) * 8));

  f32x4 acc_o[4] = {};
  float m_run[4] = {-1e30f, -1e30f, -1e30f, -1e30f};
  float l_run[4] = {0.f, 0.f, 0.f, 0.f};
  const int qrow0 = qt * 64 + wid * 16 + ((lane >> 4) << 2);

  for (int kt = 0; kt <= qt; ++kt) {
    __syncthreads();
#pragma unroll
    for (int i = 0; i < 2; ++i) {
      int row = i * 32 + (tid >> 3);
      gl_lds16(K + base + (size_t)(kt * 64 + row) * 64 +
                   (((tid & 7) ^ (row & 7)) << 3),
               (char*)Ks + i * 4096 + wid * 1024);
      gl_lds16(Vt + base + (size_t)row * 2048 + kt * 64 +
                   (((tid & 7) ^ (row & 7)) << 3),
               (char*)Vs + i * 4096 + wid * 1024);
    }
    __syncthreads();

    f32x4 s[4] = {};
#pragma unroll
    for (int kk = 0; kk < 2; ++kk) {
      const int kc = kk * 32 + (lane >> 4) * 8;
#pragma unroll
      for (int n = 0; n < 4; ++n) {
        bf16x8 bk = *(const bf16x8*)(Ks + swzh(n * 16 + (lane & 15), kc));
        s[n] = __builtin_amdgcn_mfma_f32_16x16x32_bf16(qf[kk], bk, s[n], 0, 0, 0);
      }
    }

    const int kb = kt * 64;
    const bool diag = (kt == qt);
#pragma unroll
    for (int r = 0; r < 4; ++r) {
      const int q = qrow0 + r;
      if (diag) {
#pragma unroll
        for (int n = 0; n < 4; ++n)
          if (kb + n * 16 + (lane & 15) > q) s[n][r] = -1e30f;
      }
      float mx = fmaxf(fmaxf(s[0][r], s[1][r]), fmaxf(s[2][r], s[3][r]));
#pragma unroll
      for (int off = 1; off < 16; off <<= 1)
        mx = fmaxf(mx, __shfl_xor(mx, off, 64));
      const float mn = fmaxf(m_run[r], mx);
      const float alpha = exp2f(m_run[r] - mn);
      float rs = 0.f;
#pragma unroll
      for (int n = 0; n < 4; ++n) {
        const float p = exp2f(s[n][r] - mn);
        s[n][r] = p;
        rs += p;
      }
#pragma unroll
      for (int off = 1; off < 16; off <<= 1) rs += __shfl_xor(rs, off, 64);
      m_run[r] = mn;
      l_run[r] = l_run[r] * alpha + rs;
      const int prow = wid * 16 + (lane >> 4) * 4 + r;
#pragma unroll
      for (int n = 0; n < 4; ++n) {
        acc_o[n][r] *= alpha;
        Ps[swzh(prow, n * 16 + (lane & 15))] = f2bf(s[n][r]);
      }
    }
    asm volatile("s_waitcnt lgkmcnt(0)" ::: "memory");

#pragma unroll
    for (int kk = 0; kk < 2; ++kk) {
      const int kc = kk * 32 + (lane >> 4) * 8;
      bf16x8 pf = *(const bf16x8*)(Ps + swzh(wid * 16 + (lane & 15), kc));
#pragma unroll
      for (int n = 0; n < 4; ++n) {
        bf16x8 vf = *(const bf16x8*)(Vs + swzh(n * 16 + (lane & 15), kc));
        acc_o[n] = __builtin_amdgcn_mfma_f32_16x16x32_bf16(pf, vf, acc_o[n], 0, 0, 0);
      }
    }
  }

#pragma unroll
  for (int r = 0; r < 4; ++r) {
    const int q = qrow0 + r;
    const float rl = 1.0f / l_run[r];
#pragma unroll
    for (int n = 0; n < 4; ++n) {
      const int dh = n * 16 + (lane & 15);
      ctx[((size_t)(b * 2048 + q)) * 1024 + h * 64 + dh] = f2bf(acc_o[n][r] * rl);
    }
    if (h == 0 && (lane & 15) == 0)
      stats[b * 2048 + q] = make_float2(m_run[r], l_run[r]);
  }
}

// ---------------- top_attn (head 0) probabilities -------------------------
__global__ __launch_bounds__(256) void probs_k(const u16* __restrict__ Q,
                                               const u16* __restrict__ K,
                                               const float2* __restrict__ stats,
                                               float* __restrict__ out) {
  const int tid = threadIdx.x, lane = tid & 63, wid = tid >> 6;
  const int kt2 = blockIdx.x, qt = blockIdx.y, b = blockIdx.z;
  const int q0 = qt * 64, c0 = kt2 * 128;
  float* ot = out + ((size_t)b * 2048 + q0) * 2048 + c0;

  if (c0 > q0 + 63) {  // whole tile masked -> zero-fill
    const float4 z = make_float4(0.f, 0.f, 0.f, 0.f);
#pragma unroll
    for (int i = 0; i < 8; ++i) {
      const int idx = i * 256 + tid;
      *(float4*)(ot + (size_t)(idx >> 5) * 2048 + ((idx & 31) << 2)) = z;
    }
    return;
  }

  __shared__ alignas(16) u16 Qs[4096], Ks2[8192];
  const size_t base = (size_t)(b * 16) * 2048 * 64;  // h = 0
#pragma unroll
  for (int i = 0; i < 2; ++i) {
    int row = i * 32 + (tid >> 3);
    gl_lds16(Q + base + (size_t)(q0 + row) * 64 + (((tid & 7) ^ (row & 7)) << 3),
             (char*)Qs + i * 4096 + wid * 1024);
  }
#pragma unroll
  for (int i = 0; i < 4; ++i) {
    int row = i * 32 + (tid >> 3);
    gl_lds16(K + base + (size_t)(c0 + row) * 64 + (((tid & 7) ^ (row & 7)) << 3),
             (char*)Ks2 + i * 4096 + wid * 1024);
  }
  __syncthreads();

  f32x4 s[8] = {};
#pragma unroll
  for (int kk = 0; kk < 2; ++kk) {
    const int kc = kk * 32 + (lane >> 4) * 8;
    bf16x8 aq = *(const bf16x8*)(Qs + swzh(wid * 16 + (lane & 15), kc));
#pragma unroll
    for (int n = 0; n < 8; ++n) {
      bf16x8 bk = *(const bf16x8*)(Ks2 + swzh(n * 16 + (lane & 15), kc));
      s[n] = __builtin_amdgcn_mfma_f32_16x16x32_bf16(aq, bk, s[n], 0, 0, 0);
    }
  }

#pragma unroll
  for (int r = 0; r < 4; ++r) {
    const int q = q0 + wid * 16 + ((lane >> 4) << 2) + r;
    const float2 st = stats[b * 2048 + q];
    const float rl = 1.0f / st.y;
#pragma unroll
    for (int n = 0; n < 8; ++n) {
      const int kp = c0 + n * 16 + (lane & 15);
      out[((size_t)b * 2048 + q) * 2048 + kp] =
          (kp <= q) ? exp2f(s[n][r] - st.x) * rl : 0.f;
    }
  }
}

extern "C" void kernel_launch(void* const* d_in, const int* in_sizes, int n_in,
                              void* d_out, int out_size, void* d_ws,
                              size_t ws_size, hipStream_t stream) {
  (void)in_sizes; (void)n_in; (void)out_size; (void)ws_size;
  const float* key = (const float*)d_in[0];
  const float* value = (const float*)d_in[1];
  const float* query = (const float*)d_in[2];
  // d_in[3] = mask (causal triu k=1) -- implemented analytically
  const float* Wk = (const float*)d_in[4];
  const float* bk = (const float*)d_in[5];
  const float* Wv = (const float*)d_in[6];
  const float* bv = (const float*)d_in[7];
  const float* Wq = (const float*)d_in[8];
  const float* bq = (const float*)d_in[9];
  const float* Wo = (const float*)d_in[10];
  const float* bo = (const float*)d_in[11];

  char* ws = (char*)d_ws;  // needs ~75.6 MB
  u16* WtK = (u16*)(ws);
  u16* WtV = (u16*)(ws + (2u << 20));
  u16* WtQ = (u16*)(ws + (4u << 20));
  u16* WtO = (u16*)(ws + (6u << 20));
  u16* Kup = (u16*)(ws + (8u << 20));   // [b][h][l][dh] bf16, 16 MB
  u16* Qup = (u16*)(ws + (24u << 20));  // [b][h][l][dh] bf16, 16 MB
  u16* Vt  = (u16*)(ws + (40u << 20));  // [b][h][dh][l] bf16, 16 MB
  u16* ctx = (u16*)(ws + (56u << 20));  // [b][l][1024] bf16, 16 MB
  float2* stats = (float2*)(ws + (72u << 20));  // [b*2048] (m_log2, lsum)

  dim3 tg(16, 16);
  wtrans_k<<<tg, 256, 0, stream>>>(Wk, WtK);
  wtrans_k<<<tg, 256, 0, stream>>>(Wv, WtV);
  wtrans_k<<<tg, 256, 0, stream>>>(Wq, WtQ);
  wtrans_k<<<tg, 256, 0, stream>>>(Wo, WtO);

  // Q scale folds 1/sqrt(DH) and log2(e) so softmax runs on exp2 directly.
  const float qscale = 0.125f * 1.44269504088896340736f;
  gemm_k<true, 0><<<512, 256, 0, stream>>>(key, WtK, bk, Kup, 1.0f);
  gemm_k<true, 1><<<512, 256, 0, stream>>>(value, WtV, bv, Vt, 1.0f);
  gemm_k<true, 0><<<512, 256, 0, stream>>>(query, WtQ, bq, Qup, qscale);

  attn_k<<<dim3(64, 32), 256, 0, stream>>>(Qup, Kup, Vt, ctx, stats);

  float* out = (float*)d_out;
  probs_k<<<dim3(16, 32, 4), 256, 0, stream>>>(Qup, Kup, stats,
                                               out + (size_t)8388608);

  gemm_k<false, 2><<<512, 256, 0, stream>>>(ctx, WtO, bo, out, 1.0f);
}

// Round 3
// 267.651 us; speedup vs baseline: 1.4670x; 1.3214x over previous
//
#include <hip/hip_runtime.h>
#include <hip/hip_bf16.h>
#include <stdint.h>

typedef unsigned short u16;
typedef unsigned int u32;
typedef __attribute__((ext_vector_type(8))) short bf16x8;
typedef __attribute__((ext_vector_type(4))) float f32x4;
typedef __attribute__((address_space(1))) unsigned int as1u;
typedef __attribute__((address_space(3))) unsigned int as3u;

#define DEV __device__ __forceinline__

DEV u16 f2bf(float f) {
  union { float f; unsigned u; } v; v.f = f;
  unsigned r = v.u + 0x7FFFu + ((v.u >> 16) & 1u);  // RNE
  return (u16)(r >> 16);
}

DEV void gl_lds16(const void* g, void* l) {
  __builtin_amdgcn_global_load_lds(
      reinterpret_cast<as1u*>(reinterpret_cast<uintptr_t>(g)),
      reinterpret_cast<as3u*>(reinterpret_cast<uintptr_t>(l)), 16, 0, 0);
}

// XOR-swizzled index helpers. Tiles are [rows][64] elements.
DEV int swzh(int r, int c) { return r * 64 + (c ^ ((r & 7) << 3)); }
DEV int swzf(int r, int c) { return r * 64 + (c ^ ((r & 7) << 2)); }

// ---------------- weight transpose+convert:  Wt[n][k] = bf16(W[k][n]) ------
__global__ __launch_bounds__(256) void wtrans_k(const float* __restrict__ W,
                                                u16* __restrict__ Wt) {
  __shared__ float t[64][65];
  const int tid = threadIdx.x;
  const int n0 = blockIdx.x * 64, k0 = blockIdx.y * 64;
  const int c = tid & 63, r4 = tid >> 6;
#pragma unroll
  for (int i = 0; i < 16; ++i) {
    int r = r4 * 16 + i;
    t[r][c] = W[(size_t)(k0 + r) * 1024 + n0 + c];
  }
  __syncthreads();
#pragma unroll
  for (int i = 0; i < 16; ++i) {
    int r = r4 * 16 + i;
    Wt[(size_t)(n0 + r) * 1024 + k0 + c] = f2bf(t[c][r]);
  }
}

// ---------------- GEMM: C = (A @ Wt^T + bias) * scale ----------------------
template <bool AF32, int OMODE>
__global__ __launch_bounds__(256) void gemm_k(const void* __restrict__ Ap,
                                              const u16* __restrict__ Bt,
                                              const float* __restrict__ bias,
                                              void* __restrict__ Cp,
                                              float scale) {
  constexpr int K = 1024;
  __shared__ alignas(16) char smem[AF32 ? 49152 : 32768];
  float* Asf = (float*)smem;
  u16* Ash = (u16*)smem;
  u16* Bs = (u16*)(smem + (AF32 ? 32768 : 16384));

  const int tid = threadIdx.x;
  const int lane = tid & 63, wid = tid >> 6;
  const int brow = (blockIdx.x >> 3) * 128;
  const int bcol = (blockIdx.x & 7) * 128;
  const int wr = (wid >> 1) * 64, wc = (wid & 1) * 64;

  const float* Af = (const float*)Ap;
  const u16* Ah = (const u16*)Ap;

  f32x4 acc[4][4] = {};

  for (int kt = 0; kt < K; kt += 64) {
    __syncthreads();
    if constexpr (AF32) {
#pragma unroll
      for (int i = 0; i < 8; ++i) {
        int row = i * 16 + (tid >> 4);
        gl_lds16(Af + (size_t)(brow + row) * K + kt +
                     (((tid & 15) ^ (row & 7)) << 2),
                 smem + i * 4096 + wid * 1024);
      }
    } else {
#pragma unroll
      for (int i = 0; i < 4; ++i) {
        int row = i * 32 + (tid >> 3);
        gl_lds16(Ah + (size_t)(brow + row) * K + kt +
                     (((tid & 7) ^ (row & 7)) << 3),
                 smem + i * 4096 + wid * 1024);
      }
    }
#pragma unroll
    for (int i = 0; i < 4; ++i) {
      int row = i * 32 + (tid >> 3);
      gl_lds16(Bt + (size_t)(bcol + row) * K + kt +
                   (((tid & 7) ^ (row & 7)) << 3),
               (char*)Bs + i * 4096 + wid * 1024);
    }
    __syncthreads();

#pragma unroll
    for (int kk = 0; kk < 2; ++kk) {
      const int kcol = kk * 32 + (lane >> 4) * 8;
      bf16x8 a[4], bfr[4];
#pragma unroll
      for (int m = 0; m < 4; ++m) {
        const int row = wr + m * 16 + (lane & 15);
        if constexpr (AF32) {
          float4 x0 = *(const float4*)(Asf + swzf(row, kcol));
          float4 x1 = *(const float4*)(Asf + swzf(row, kcol + 4));
          bf16x8 t;
          t[0] = (short)f2bf(x0.x); t[1] = (short)f2bf(x0.y);
          t[2] = (short)f2bf(x0.z); t[3] = (short)f2bf(x0.w);
          t[4] = (short)f2bf(x1.x); t[5] = (short)f2bf(x1.y);
          t[6] = (short)f2bf(x1.z); t[7] = (short)f2bf(x1.w);
          a[m] = t;
        } else {
          a[m] = *(const bf16x8*)(Ash + swzh(row, kcol));
        }
      }
#pragma unroll
      for (int n = 0; n < 4; ++n)
        bfr[n] = *(const bf16x8*)(Bs + swzh(wc + n * 16 + (lane & 15), kcol));
#pragma unroll
      for (int m = 0; m < 4; ++m)
#pragma unroll
        for (int n = 0; n < 4; ++n)
          acc[m][n] = __builtin_amdgcn_mfma_f32_16x16x32_bf16(
              a[m], bfr[n], acc[m][n], 0, 0, 0);
    }
  }

#pragma unroll
  for (int m = 0; m < 4; ++m) {
    const int row0 = brow + wr + m * 16 + ((lane >> 4) << 2);
#pragma unroll
    for (int n = 0; n < 4; ++n) {
      const int col = bcol + wc + n * 16 + (lane & 15);
      const float bv = bias[col];
#pragma unroll
      for (int r = 0; r < 4; ++r) {
        const int row = row0 + r;
        const float val = (acc[m][n][r] + bv) * scale;
        if constexpr (OMODE == 0) {
          const int b = row >> 11, l = row & 2047, h = col >> 6, dh = col & 63;
          ((u16*)Cp)[((size_t)((b << 4) + h) * 2048 + l) * 64 + dh] = f2bf(val);
        } else if constexpr (OMODE == 1) {
          const int b = row >> 11, l = row & 2047, h = col >> 6, dh = col & 63;
          ((u16*)Cp)[((size_t)((b << 4) + h) * 64 + dh) * 2048 + l] = f2bf(val);
        } else {
          ((float*)Cp)[(size_t)row * 1024 + col] = val;
        }
      }
    }
  }
}

// ---------------- flash attention v2: swapped QK^T, in-lane softmax --------
// Q,K: bf16 [bh][l][64] (Q pre-scaled by 0.125*log2e); Vt: bf16 [bh][64][l]
// Per wave: 16 q-rows. Swapped QK (A=K, B=Q) => lane holds 16 kv-scores of
// q = wid*16+(lane&15). Softmax: 15 in-lane fmax + 2 shfl. Double-buffered
// K/V staging with stage-at-top, one barrier per tile. Defer-max THR=8 (log2).
__global__ __launch_bounds__(256) void attn_k(const u16* __restrict__ Q,
                                              const u16* __restrict__ K,
                                              const u16* __restrict__ Vt,
                                              u16* __restrict__ ctx,
                                              float2* __restrict__ stats) {
  const int tid = threadIdx.x, lane = tid & 63, wid = tid >> 6;
  const int bh = blockIdx.x;
  const int qt = (int)(gridDim.y - 1) - (int)blockIdx.y;  // heavy blocks first
  const int b = bh >> 4, h = bh & 15;
  const size_t base = (size_t)bh * 2048 * 64;

  __shared__ alignas(16) u16 Ks[2][4096], Vs[2][4096], Ps[4096];

  // Q direct global->reg: B-frag q = wid*16+(lane&15), k = (lane>>4)*8 + kk*32
  bf16x8 qf[2];
  {
    const u16* qp = Q + base + (size_t)(qt * 64 + wid * 16 + (lane & 15)) * 64 +
                    ((lane >> 4) << 3);
    qf[0] = *(const bf16x8*)(qp);
    qf[1] = *(const bf16x8*)(qp + 32);
  }

  // cooperative K/V staging: LDS row r = i*32 + wid*8 + (lane>>3); linear
  // dest, source column pre-XOR-swizzled (16B granular, r&7 == lane>>3).
  const int srow = wid * 8 + (lane >> 3);
  const int scol = ((lane & 7) ^ (lane >> 3)) << 3;  // elements
  auto stage = [&](int kt2, int buf) {
#pragma unroll
    for (int i = 0; i < 2; ++i) {
      const int r = i * 32 + srow;
      gl_lds16(K + base + (size_t)(kt2 * 64 + r) * 64 + scol,
               (char*)Ks + buf * 8192 + i * 4096 + wid * 1024);
      gl_lds16(Vt + base + (size_t)r * 2048 + kt2 * 64 + scol,
               (char*)Vs + buf * 8192 + i * 4096 + wid * 1024);
    }
  };

  f32x4 acc_o[4] = {};
  float m_run = -1e30f, l_run = 0.f;
  const int q = qt * 64 + wid * 16 + (lane & 15);  // this lane's softmax row
  const int g = lane >> 4;
  const int rmask7 = lane & 7;  // (row&7) for rows == lane&15 patterns

  stage(0, 0);
  __syncthreads();

  int cur = 0;
  for (int kt = 0; kt <= qt; ++kt) {
    if (kt < qt) stage(kt + 1, cur ^ 1);

    // QK^T swapped: s[n] rows = kv (n*16 + g*4 + r), col = q
    f32x4 s[4] = {};
#pragma unroll
    for (int kk = 0; kk < 2; ++kk) {
      const int kcb = (kk * 64 + g * 16);
#pragma unroll
      for (int n = 0; n < 4; ++n) {
        const int row = n * 16 + (lane & 15);
        bf16x8 kf = *(const bf16x8*)((char*)Ks + cur * 8192 + row * 128 +
                                     (kcb ^ (rmask7 << 4)));
        s[n] = __builtin_amdgcn_mfma_f32_16x16x32_bf16(kf, qf[kk], s[n], 0, 0, 0);
      }
    }

    if (kt == qt) {  // diagonal masking: kv > q -> -inf
      const int kb = kt * 64 + g * 4;
#pragma unroll
      for (int n = 0; n < 4; ++n)
#pragma unroll
        for (int r = 0; r < 4; ++r)
          if (kb + n * 16 + r > q) s[n][r] = -1e30f;
    }

    // in-lane max over 16 + cross-group (2 shfl)
    float mx = s[0][0];
#pragma unroll
    for (int n = 0; n < 4; ++n)
#pragma unroll
      for (int r = 0; r < 4; ++r) mx = fmaxf(mx, s[n][r]);
    mx = fmaxf(mx, __shfl_xor(mx, 16, 64));
    mx = fmaxf(mx, __shfl_xor(mx, 32, 64));

    // defer-max: rescale only when max grows past THR (log2 units)
    if (__any(mx - m_run > 8.0f)) {
      const float mn = fmaxf(m_run, mx);
      const float alpha = exp2f(m_run - mn);
      m_run = mn;
      l_run *= alpha;
#pragma unroll
      for (int r = 0; r < 4; ++r) {
        const float ar = __shfl(alpha, (g << 2) + r, 64);
#pragma unroll
        for (int n = 0; n < 4; ++n) acc_o[n][r] *= ar;
      }
    }

    // P = exp2(s - m_run); row sum
    float rs = 0.f;
#pragma unroll
    for (int n = 0; n < 4; ++n)
#pragma unroll
      for (int r = 0; r < 4; ++r) {
        const float pv = exp2f(s[n][r] - m_run);
        s[n][r] = pv;
        rs += pv;
      }
    rs += __shfl_xor(rs, 16, 64);
    rs += __shfl_xor(rs, 32, 64);
    l_run += rs;

    // P -> LDS: packed b64 writes, row = q_local (lane&15), swizzled 16B-gran
#pragma unroll
    for (int n = 0; n < 4; ++n) {
      union { __hip_bfloat162 h2[2]; uint2 u; } pk;
      pk.h2[0] = __float22bfloat162_rn(make_float2(s[n][0], s[n][1]));
      pk.h2[1] = __float22bfloat162_rn(make_float2(s[n][2], s[n][3]));
      *(uint2*)((char*)Ps + wid * 2048 + (lane & 15) * 128 +
                ((n * 32 + g * 8) ^ (rmask7 << 4))) = pk.u;
    }

    // PV: A = P[q_local][kv], B = V^T[dh][kv]
#pragma unroll
    for (int kk = 0; kk < 2; ++kk) {
      const int kcb = (kk * 64 + g * 16);
      bf16x8 pf = *(const bf16x8*)((char*)Ps + wid * 2048 + (lane & 15) * 128 +
                                   (kcb ^ (rmask7 << 4)));
#pragma unroll
      for (int n = 0; n < 4; ++n) {
        const int row = n * 16 + (lane & 15);
        bf16x8 vf = *(const bf16x8*)((char*)Vs + cur * 8192 + row * 128 +
                                     (kcb ^ (rmask7 << 4)));
        acc_o[n] = __builtin_amdgcn_mfma_f32_16x16x32_bf16(pf, vf, acc_o[n], 0, 0, 0);
      }
    }
    __syncthreads();
    cur ^= 1;
  }

  // epilogue: gather 1/l for output rows q_out = wid*16 + g*4 + r
  float linv[4];
#pragma unroll
  for (int r = 0; r < 4; ++r)
    linv[r] = 1.0f / __shfl(l_run, (g << 2) + r, 64);
#pragma unroll
  for (int r = 0; r < 4; ++r) {
    const int qo = qt * 64 + wid * 16 + (g << 2) + r;
#pragma unroll
    for (int n = 0; n < 4; ++n) {
      const int dh = n * 16 + (lane & 15);
      ctx[((size_t)(b * 2048 + qo)) * 1024 + h * 64 + dh] =
          f2bf(acc_o[n][r] * linv[r]);
    }
  }
  if (h == 0 && g == 0)
    stats[b * 2048 + q] = make_float2(m_run, l_run);
}

// ---------------- top_attn (head 0) probabilities -------------------------
__global__ __launch_bounds__(256) void probs_k(const u16* __restrict__ Q,
                                               const u16* __restrict__ K,
                                               const float2* __restrict__ stats,
                                               float* __restrict__ out) {
  const int tid = threadIdx.x, lane = tid & 63, wid = tid >> 6;
  const int kt2 = blockIdx.x, qt = blockIdx.y, b = blockIdx.z;
  const int q0 = qt * 64, c0 = kt2 * 128;
  float* ot = out + ((size_t)b * 2048 + q0) * 2048 + c0;

  if (c0 > q0 + 63) {  // whole tile masked -> zero-fill
    const float4 z = make_float4(0.f, 0.f, 0.f, 0.f);
#pragma unroll
    for (int i = 0; i < 8; ++i) {
      const int idx = i * 256 + tid;
      *(float4*)(ot + (size_t)(idx >> 5) * 2048 + ((idx & 31) << 2)) = z;
    }
    return;
  }

  __shared__ alignas(16) u16 Qs[4096], Ks2[8192];
  const size_t base = (size_t)(b * 16) * 2048 * 64;  // h = 0
#pragma unroll
  for (int i = 0; i < 2; ++i) {
    int row = i * 32 + (tid >> 3);
    gl_lds16(Q + base + (size_t)(q0 + row) * 64 + (((tid & 7) ^ (row & 7)) << 3),
             (char*)Qs + i * 4096 + wid * 1024);
  }
#pragma unroll
  for (int i = 0; i < 4; ++i) {
    int row = i * 32 + (tid >> 3);
    gl_lds16(K + base + (size_t)(c0 + row) * 64 + (((tid & 7) ^ (row & 7)) << 3),
             (char*)Ks2 + i * 4096 + wid * 1024);
  }
  __syncthreads();

  f32x4 s[8] = {};
#pragma unroll
  for (int kk = 0; kk < 2; ++kk) {
    const int kc = kk * 32 + (lane >> 4) * 8;
    bf16x8 aq = *(const bf16x8*)(Qs + swzh(wid * 16 + (lane & 15), kc));
#pragma unroll
    for (int n = 0; n < 8; ++n) {
      bf16x8 bk = *(const bf16x8*)(Ks2 + swzh(n * 16 + (lane & 15), kc));
      s[n] = __builtin_amdgcn_mfma_f32_16x16x32_bf16(aq, bk, s[n], 0, 0, 0);
    }
  }

#pragma unroll
  for (int r = 0; r < 4; ++r) {
    const int q = q0 + wid * 16 + ((lane >> 4) << 2) + r;
    const float2 st = stats[b * 2048 + q];
    const float rl = 1.0f / st.y;
#pragma unroll
    for (int n = 0; n < 8; ++n) {
      const int kp = c0 + n * 16 + (lane & 15);
      out[((size_t)b * 2048 + q) * 2048 + kp] =
          (kp <= q) ? exp2f(s[n][r] - st.x) * rl : 0.f;
    }
  }
}

extern "C" void kernel_launch(void* const* d_in, const int* in_sizes, int n_in,
                              void* d_out, int out_size, void* d_ws,
                              size_t ws_size, hipStream_t stream) {
  (void)in_sizes; (void)n_in; (void)out_size; (void)ws_size;
  const float* key = (const float*)d_in[0];
  const float* value = (const float*)d_in[1];
  const float* query = (const float*)d_in[2];
  const float* Wk = (const float*)d_in[4];
  const float* bk = (const float*)d_in[5];
  const float* Wv = (const float*)d_in[6];
  const float* bv = (const float*)d_in[7];
  const float* Wq = (const float*)d_in[8];
  const float* bq = (const float*)d_in[9];
  const float* Wo = (const float*)d_in[10];
  const float* bo = (const float*)d_in[11];

  char* ws = (char*)d_ws;  // needs ~75.6 MB
  u16* WtK = (u16*)(ws);
  u16* WtV = (u16*)(ws + (2u << 20));
  u16* WtQ = (u16*)(ws + (4u << 20));
  u16* WtO = (u16*)(ws + (6u << 20));
  u16* Kup = (u16*)(ws + (8u << 20));   // [b][h][l][dh] bf16
  u16* Qup = (u16*)(ws + (24u << 20));  // [b][h][l][dh] bf16
  u16* Vt  = (u16*)(ws + (40u << 20));  // [b][h][dh][l] bf16
  u16* ctx = (u16*)(ws + (56u << 20));  // [b][l][1024] bf16
  float2* stats = (float2*)(ws + (72u << 20));  // [b*2048] (m_log2, lsum)

  dim3 tg(16, 16);
  wtrans_k<<<tg, 256, 0, stream>>>(Wk, WtK);
  wtrans_k<<<tg, 256, 0, stream>>>(Wv, WtV);
  wtrans_k<<<tg, 256, 0, stream>>>(Wq, WtQ);
  wtrans_k<<<tg, 256, 0, stream>>>(Wo, WtO);

  // Q scale folds 1/sqrt(DH) and log2(e) so softmax runs on exp2 directly.
  const float qscale = 0.125f * 1.44269504088896340736f;
  gemm_k<true, 0><<<512, 256, 0, stream>>>(key, WtK, bk, Kup, 1.0f);
  gemm_k<true, 1><<<512, 256, 0, stream>>>(value, WtV, bv, Vt, 1.0f);
  gemm_k<true, 0><<<512, 256, 0, stream>>>(query, WtQ, bq, Qup, qscale);

  attn_k<<<dim3(64, 32), 256, 0, stream>>>(Qup, Kup, Vt, ctx, stats);

  float* out = (float*)d_out;
  probs_k<<<dim3(16, 32, 4), 256, 0, stream>>>(Qup, Kup, stats,
                                               out + (size_t)8388608);

  gemm_k<false, 2><<<512, 256, 0, stream>>>(ctx, WtO, bo, out, 1.0f);
}

// Round 6
// 249.539 us; speedup vs baseline: 1.5735x; 1.0726x over previous
//
#include <hip/hip_runtime.h>
#include <hip/hip_bf16.h>
#include <stdint.h>

typedef unsigned short u16;
typedef unsigned int u32;
typedef __attribute__((ext_vector_type(8))) short bf16x8;
typedef __attribute__((ext_vector_type(4))) float f32x4;
typedef __attribute__((address_space(1))) unsigned int as1u;
typedef __attribute__((address_space(3))) unsigned int as3u;

#define DEV __device__ __forceinline__

DEV u16 f2bf(float f) {
  union { float f; unsigned u; } v; v.f = f;
  unsigned r = v.u + 0x7FFFu + ((v.u >> 16) & 1u);  // RNE
  return (u16)(r >> 16);
}

// hardware packed fp32->bf16 convert (no builtin on gfx950)
DEV u32 cvtpk(float lo, float hi) {
  u32 r;
  asm("v_cvt_pk_bf16_f32 %0, %1, %2" : "=v"(r) : "v"(lo), "v"(hi));
  return r;
}

DEV void gl_lds16(const void* g, void* l) {
  __builtin_amdgcn_global_load_lds(
      reinterpret_cast<as1u*>(reinterpret_cast<uintptr_t>(g)),
      reinterpret_cast<as3u*>(reinterpret_cast<uintptr_t>(l)), 16, 0, 0);
}

// XOR-swizzled index helpers. Tiles are [rows][64] elements.
DEV int swzh(int r, int c) { return r * 64 + (c ^ ((r & 7) << 3)); }
DEV int swzf(int r, int c) { return r * 64 + (c ^ ((r & 7) << 2)); }

// ---------------- weight transpose+convert (all 4 weights, z-indexed) ------
__global__ __launch_bounds__(256) void wtrans4_k(
    const float* __restrict__ W0, const float* __restrict__ W1,
    const float* __restrict__ W2, const float* __restrict__ W3,
    u16* __restrict__ T0, u16* __restrict__ T1, u16* __restrict__ T2,
    u16* __restrict__ T3) {
  const int z = blockIdx.z;
  const float* W = z == 0 ? W0 : z == 1 ? W1 : z == 2 ? W2 : W3;
  u16* Wt = z == 0 ? T0 : z == 1 ? T1 : z == 2 ? T2 : T3;
  __shared__ float t[64][65];
  const int tid = threadIdx.x;
  const int n0 = blockIdx.x * 64, k0 = blockIdx.y * 64;
  const int c = tid & 63, r4 = tid >> 6;
#pragma unroll
  for (int i = 0; i < 16; ++i) {
    int r = r4 * 16 + i;
    t[r][c] = W[(size_t)(k0 + r) * 1024 + n0 + c];
  }
  __syncthreads();
#pragma unroll
  for (int i = 0; i < 16; ++i) {
    int r = r4 * 16 + i;
    Wt[(size_t)(n0 + r) * 1024 + k0 + c] = f2bf(t[c][r]);
  }
}

// ---------------- fused QKV projection GEMM (z = 0:K, 1:V, 2:Q) ------------
// A fp32 [8192][1024]; Bt bf16 [1024][1024]. z=1 writes V-transposed.
__global__ __launch_bounds__(256) void qkvgemm_k(
    const float* __restrict__ Akey, const float* __restrict__ Aval,
    const float* __restrict__ Aqry, const u16* __restrict__ BtK,
    const u16* __restrict__ BtV, const u16* __restrict__ BtQ,
    const float* __restrict__ bk, const float* __restrict__ bv,
    const float* __restrict__ bq, u16* __restrict__ Kup, u16* __restrict__ Vt,
    u16* __restrict__ Qup, float qscale) {
  constexpr int K = 1024;
  const int z = blockIdx.z;
  const float* Af = z == 0 ? Akey : z == 1 ? Aval : Aqry;
  const u16* Bt = z == 0 ? BtK : z == 1 ? BtV : BtQ;
  const float* bias = z == 0 ? bk : z == 1 ? bv : bq;
  u16* Cp = z == 0 ? Kup : z == 1 ? Vt : Qup;
  const float scale = z == 2 ? qscale : 1.0f;

  __shared__ alignas(16) char smem[49152];
  float* Asf = (float*)smem;
  u16* Bs = (u16*)(smem + 32768);

  const int tid = threadIdx.x;
  const int lane = tid & 63, wid = tid >> 6;
  const int brow = (blockIdx.x >> 3) * 128;
  const int bcol = (blockIdx.x & 7) * 128;
  const int wr = (wid >> 1) * 64, wc = (wid & 1) * 64;

  f32x4 acc[4][4] = {};

  for (int kt = 0; kt < K; kt += 64) {
    __syncthreads();
#pragma unroll
    for (int i = 0; i < 8; ++i) {
      int row = i * 16 + (tid >> 4);
      gl_lds16(Af + (size_t)(brow + row) * K + kt +
                   (((tid & 15) ^ (row & 7)) << 2),
               smem + i * 4096 + wid * 1024);
    }
#pragma unroll
    for (int i = 0; i < 4; ++i) {
      int row = i * 32 + (tid >> 3);
      gl_lds16(Bt + (size_t)(bcol + row) * K + kt +
                   (((tid & 7) ^ (row & 7)) << 3),
               (char*)Bs + i * 4096 + wid * 1024);
    }
    __syncthreads();

#pragma unroll
    for (int kk = 0; kk < 2; ++kk) {
      const int kcol = kk * 32 + (lane >> 4) * 8;
      bf16x8 a[4], bfr[4];
#pragma unroll
      for (int m = 0; m < 4; ++m) {
        const int row = wr + m * 16 + (lane & 15);
        float4 x0 = *(const float4*)(Asf + swzf(row, kcol));
        float4 x1 = *(const float4*)(Asf + swzf(row, kcol + 4));
        union { u32 w[4]; bf16x8 v; } u;
        u.w[0] = cvtpk(x0.x, x0.y);
        u.w[1] = cvtpk(x0.z, x0.w);
        u.w[2] = cvtpk(x1.x, x1.y);
        u.w[3] = cvtpk(x1.z, x1.w);
        a[m] = u.v;
      }
#pragma unroll
      for (int n = 0; n < 4; ++n)
        bfr[n] = *(const bf16x8*)(Bs + swzh(wc + n * 16 + (lane & 15), kcol));
#pragma unroll
      for (int m = 0; m < 4; ++m)
#pragma unroll
        for (int n = 0; n < 4; ++n)
          acc[m][n] = __builtin_amdgcn_mfma_f32_16x16x32_bf16(
              a[m], bfr[n], acc[m][n], 0, 0, 0);
    }
  }

#pragma unroll
  for (int m = 0; m < 4; ++m) {
    const int row0 = brow + wr + m * 16 + ((lane >> 4) << 2);
#pragma unroll
    for (int n = 0; n < 4; ++n) {
      const int col = bcol + wc + n * 16 + (lane & 15);
      const float bv2 = bias[col];
#pragma unroll
      for (int r = 0; r < 4; ++r) {
        const int row = row0 + r;
        const float val = (acc[m][n][r] + bv2) * scale;
        const int b = row >> 11, l = row & 2047, h = col >> 6, dh = col & 63;
        if (z == 1)
          Cp[((size_t)((b << 4) + h) * 64 + dh) * 2048 + l] = f2bf(val);
        else
          Cp[((size_t)((b << 4) + h) * 2048 + l) * 64 + dh] = f2bf(val);
      }
    }
  }
}

// ---------------- output GEMM: C = ctx @ Wt^T + bias (fp32 out) ------------
__global__ __launch_bounds__(256) void outgemm_k(const u16* __restrict__ Ah,
                                                 const u16* __restrict__ Bt,
                                                 const float* __restrict__ bias,
                                                 float* __restrict__ Cp) {
  constexpr int K = 1024;
  __shared__ alignas(16) char smem[32768];
  u16* Ash = (u16*)smem;
  u16* Bs = (u16*)(smem + 16384);

  const int tid = threadIdx.x;
  const int lane = tid & 63, wid = tid >> 6;
  const int brow = (blockIdx.x >> 3) * 128;
  const int bcol = (blockIdx.x & 7) * 128;
  const int wr = (wid >> 1) * 64, wc = (wid & 1) * 64;

  f32x4 acc[4][4] = {};

  for (int kt = 0; kt < K; kt += 64) {
    __syncthreads();
#pragma unroll
    for (int i = 0; i < 4; ++i) {
      int row = i * 32 + (tid >> 3);
      gl_lds16(Ah + (size_t)(brow + row) * K + kt +
                   (((tid & 7) ^ (row & 7)) << 3),
               smem + i * 4096 + wid * 1024);
      gl_lds16(Bt + (size_t)(bcol + row) * K + kt +
                   (((tid & 7) ^ (row & 7)) << 3),
               (char*)Bs + i * 4096 + wid * 1024);
    }
    __syncthreads();

#pragma unroll
    for (int kk = 0; kk < 2; ++kk) {
      const int kcol = kk * 32 + (lane >> 4) * 8;
      bf16x8 a[4], bfr[4];
#pragma unroll
      for (int m = 0; m < 4; ++m)
        a[m] = *(const bf16x8*)(Ash + swzh(wr + m * 16 + (lane & 15), kcol));
#pragma unroll
      for (int n = 0; n < 4; ++n)
        bfr[n] = *(const bf16x8*)(Bs + swzh(wc + n * 16 + (lane & 15), kcol));
#pragma unroll
      for (int m = 0; m < 4; ++m)
#pragma unroll
        for (int n = 0; n < 4; ++n)
          acc[m][n] = __builtin_amdgcn_mfma_f32_16x16x32_bf16(
              a[m], bfr[n], acc[m][n], 0, 0, 0);
    }
  }

#pragma unroll
  for (int m = 0; m < 4; ++m) {
    const int row0 = brow + wr + m * 16 + ((lane >> 4) << 2);
#pragma unroll
    for (int n = 0; n < 4; ++n) {
      const int col = bcol + wc + n * 16 + (lane & 15);
      const float bv2 = bias[col];
#pragma unroll
      for (int r = 0; r < 4; ++r)
        Cp[(size_t)(row0 + r) * 1024 + col] = acc[m][n][r] + bv2;
    }
  }
}

// ---------------- flash attention v5: 8 waves, 128-row Q tile --------------
// Q,K: bf16 [bh][l][64] (Q pre-scaled by 0.125*log2e); Vt: bf16 [bh][64][l]
// K AND V double-buffered; stage(kt+1) at top, compute on tile staged in the
// PREVIOUS iteration, one __syncthreads per iter.
// MASK GATE: applied iff kv_max of tile > wave's MIN q row (qminw). Using
// qmaxw here was the R3/R4 bug: the wave whose rows end exactly at the tile
// boundary (e.g. rows +48..63 vs kv_max = +63) skipped masking though rows
// 48..62 have future kvs.
__global__ __launch_bounds__(512, 6) void attn_k(const u16* __restrict__ Q,
                                                 const u16* __restrict__ K,
                                                 const u16* __restrict__ Vt,
                                                 u16* __restrict__ ctx,
                                                 float2* __restrict__ stats) {
  const int tid = threadIdx.x, lane = tid & 63, wid = tid >> 6;
  const int bh = blockIdx.x;
  const int qt = (int)(gridDim.y - 1) - (int)blockIdx.y;  // heavy blocks first
  const int b = bh >> 4, h = bh & 15;
  const size_t base = (size_t)bh * 2048 * 64;

  __shared__ alignas(16) u16 Ks[2][4096], Vs[2][4096], Ps[8192];

  // Q direct global->reg: B-frag row q = wid*16+(lane&15), k = (lane>>4)*8
  bf16x8 qf[2];
  {
    const u16* qp = Q + base +
                    (size_t)(qt * 128 + wid * 16 + (lane & 15)) * 64 +
                    ((lane >> 4) << 3);
    qf[0] = *(const bf16x8*)(qp);
    qf[1] = *(const bf16x8*)(qp + 32);
  }

  // cooperative staging: 512 threads x 16B = one 64x64 bf16 tile per call
  const int srow = tid >> 3;                        // 0..63
  const int scol = ((tid & 7) ^ (srow & 7)) << 3;   // pre-swizzled src col

  f32x4 acc_o[4] = {};
  float m_run = -1e30f, l_run = 0.f;
  const int q = qt * 128 + wid * 16 + (lane & 15);  // this lane's softmax row
  const int qminw = qt * 128 + wid * 16;            // wave's min q row
  const int qmaxw = qminw + 15;                     // wave's max q row
  const int g = lane >> 4;
  const int rmask7 = lane & 7;

  const int NT = 2 * qt + 2;

  gl_lds16(K + base + (size_t)srow * 64 + scol, (char*)Ks + tid * 16);
  gl_lds16(Vt + base + (size_t)srow * 2048 + scol, (char*)Vs + tid * 16);
  __syncthreads();

  int cur = 0;
  for (int kt = 0; kt < NT; ++kt) {
    if (kt < NT - 1) {  // prefetch next tile into the other buffer
      gl_lds16(K + base + (size_t)((kt + 1) * 64 + srow) * 64 + scol,
               (char*)Ks + (cur ^ 1) * 8192 + tid * 16);
      gl_lds16(Vt + base + (size_t)srow * 2048 + (kt + 1) * 64 + scol,
               (char*)Vs + (cur ^ 1) * 8192 + tid * 16);
    }

    if (kt * 64 <= qmaxw) {  // wave has unmasked work in this tile
      // QK^T swapped: s[n] row = kv (n*16 + g*4 + r), col = q (lane&15)
      f32x4 s[4] = {};
#pragma unroll
      for (int kk = 0; kk < 2; ++kk) {
        const int kcb = kk * 64 + g * 16;
#pragma unroll
        for (int n = 0; n < 4; ++n) {
          const int row = n * 16 + (lane & 15);
          bf16x8 kf = *(const bf16x8*)((char*)Ks + cur * 8192 + row * 128 +
                                       (kcb ^ (rmask7 << 4)));
          s[n] = __builtin_amdgcn_mfma_f32_16x16x32_bf16(kf, qf[kk], s[n],
                                                         0, 0, 0);
        }
      }

      if (kt * 64 + 63 > qminw) {  // tile reaches past some row: mask kv > q
        const int kb = kt * 64 + g * 4;
#pragma unroll
        for (int n = 0; n < 4; ++n)
#pragma unroll
          for (int r = 0; r < 4; ++r)
            if (kb + n * 16 + r > q) s[n][r] = -1e30f;
      }

      // in-lane max over 16 + cross-group (2 shfl)
      float mx = s[0][0];
#pragma unroll
      for (int n = 0; n < 4; ++n)
#pragma unroll
        for (int r = 0; r < 4; ++r) mx = fmaxf(mx, s[n][r]);
      mx = fmaxf(mx, __shfl_xor(mx, 16, 64));
      mx = fmaxf(mx, __shfl_xor(mx, 32, 64));

      if (__any(mx - m_run > 8.0f)) {  // defer-max (log2 units)
        const float mn = fmaxf(m_run, mx);
        const float alpha = exp2f(m_run - mn);
        m_run = mn;
        l_run *= alpha;
#pragma unroll
        for (int r = 0; r < 4; ++r) {
          const float ar = __shfl(alpha, (g << 2) + r, 64);
#pragma unroll
          for (int n = 0; n < 4; ++n) acc_o[n][r] *= ar;
        }
      }

      float rs = 0.f;
#pragma unroll
      for (int n = 0; n < 4; ++n)
#pragma unroll
        for (int r = 0; r < 4; ++r) {
          const float pv = exp2f(s[n][r] - m_run);
          s[n][r] = pv;
          rs += pv;
        }
      rs += __shfl_xor(rs, 16, 64);
      rs += __shfl_xor(rs, 32, 64);
      l_run += rs;

      // P -> LDS: packed b64 writes, row = q_local (lane&15)
#pragma unroll
      for (int n = 0; n < 4; ++n) {
        union { u32 w[2]; uint2 u; } pk;
        pk.w[0] = cvtpk(s[n][0], s[n][1]);
        pk.w[1] = cvtpk(s[n][2], s[n][3]);
        *(uint2*)((char*)Ps + wid * 2048 + (lane & 15) * 128 +
                  ((n * 32 + g * 8) ^ (rmask7 << 4))) = pk.u;
      }
      asm volatile("s_waitcnt lgkmcnt(0)" ::: "memory");

      // PV: A = P[q_local][kv], B = V^T[dh][kv]
#pragma unroll
      for (int kk = 0; kk < 2; ++kk) {
        const int kcb = kk * 64 + g * 16;
        bf16x8 pf = *(const bf16x8*)((char*)Ps + wid * 2048 +
                                     (lane & 15) * 128 + (kcb ^ (rmask7 << 4)));
#pragma unroll
        for (int n = 0; n < 4; ++n) {
          const int row = n * 16 + (lane & 15);
          bf16x8 vf = *(const bf16x8*)((char*)Vs + cur * 8192 + row * 128 +
                                       (kcb ^ (rmask7 << 4)));
          acc_o[n] = __builtin_amdgcn_mfma_f32_16x16x32_bf16(pf, vf, acc_o[n],
                                                             0, 0, 0);
        }
      }
    }
    __syncthreads();
    cur ^= 1;
  }

  // epilogue: gather 1/l for output rows q_out = wid*16 + g*4 + r
  float linv[4];
#pragma unroll
  for (int r = 0; r < 4; ++r)
    linv[r] = 1.0f / __shfl(l_run, (g << 2) + r, 64);
#pragma unroll
  for (int r = 0; r < 4; ++r) {
    const int qo = qt * 128 + wid * 16 + (g << 2) + r;
#pragma unroll
    for (int n = 0; n < 4; ++n) {
      const int dh = n * 16 + (lane & 15);
      ctx[((size_t)(b * 2048 + qo)) * 1024 + h * 64 + dh] =
          f2bf(acc_o[n][r] * linv[r]);
    }
  }
  if (h == 0 && g == 0)
    stats[b * 2048 + q] = make_float2(m_run, l_run);
}

// ---------------- top_attn (head 0) probabilities -------------------------
__global__ __launch_bounds__(256) void probs_k(const u16* __restrict__ Q,
                                               const u16* __restrict__ K,
                                               const float2* __restrict__ stats,
                                               float* __restrict__ out) {
  const int tid = threadIdx.x, lane = tid & 63, wid = tid >> 6;
  const int kt2 = blockIdx.x, qt = blockIdx.y, b = blockIdx.z;
  const int q0 = qt * 64, c0 = kt2 * 128;
  float* ot = out + ((size_t)b * 2048 + q0) * 2048 + c0;

  if (c0 > q0 + 63) {  // whole tile masked -> zero-fill
    const float4 z = make_float4(0.f, 0.f, 0.f, 0.f);
#pragma unroll
    for (int i = 0; i < 8; ++i) {
      const int idx = i * 256 + tid;
      *(float4*)(ot + (size_t)(idx >> 5) * 2048 + ((idx & 31) << 2)) = z;
    }
    return;
  }

  __shared__ alignas(16) u16 Qs[4096], Ks2[8192];
  const size_t base = (size_t)(b * 16) * 2048 * 64;  // h = 0
#pragma unroll
  for (int i = 0; i < 2; ++i) {
    int row = i * 32 + (tid >> 3);
    gl_lds16(Q + base + (size_t)(q0 + row) * 64 + (((tid & 7) ^ (row & 7)) << 3),
             (char*)Qs + i * 4096 + wid * 1024);
  }
#pragma unroll
  for (int i = 0; i < 4; ++i) {
    int row = i * 32 + (tid >> 3);
    gl_lds16(K + base + (size_t)(c0 + row) * 64 + (((tid & 7) ^ (row & 7)) << 3),
             (char*)Ks2 + i * 4096 + wid * 1024);
  }
  __syncthreads();

  f32x4 s[8] = {};
#pragma unroll
  for (int kk = 0; kk < 2; ++kk) {
    const int kc = kk * 32 + (lane >> 4) * 8;
    bf16x8 aq = *(const bf16x8*)(Qs + swzh(wid * 16 + (lane & 15), kc));
#pragma unroll
    for (int n = 0; n < 8; ++n) {
      bf16x8 bk = *(const bf16x8*)(Ks2 + swzh(n * 16 + (lane & 15), kc));
      s[n] = __builtin_amdgcn_mfma_f32_16x16x32_bf16(aq, bk, s[n], 0, 0, 0);
    }
  }

#pragma unroll
  for (int r = 0; r < 4; ++r) {
    const int q = q0 + wid * 16 + ((lane >> 4) << 2) + r;
    const float2 st = stats[b * 2048 + q];
    const float rl = 1.0f / st.y;
#pragma unroll
    for (int n = 0; n < 8; ++n) {
      const int kp = c0 + n * 16 + (lane & 15);
      out[((size_t)b * 2048 + q) * 2048 + kp] =
          (kp <= q) ? exp2f(s[n][r] - st.x) * rl : 0.f;
    }
  }
}

extern "C" void kernel_launch(void* const* d_in, const int* in_sizes, int n_in,
                              void* d_out, int out_size, void* d_ws,
                              size_t ws_size, hipStream_t stream) {
  (void)in_sizes; (void)n_in; (void)out_size; (void)ws_size;
  const float* key = (const float*)d_in[0];
  const float* value = (const float*)d_in[1];
  const float* query = (const float*)d_in[2];
  const float* Wk = (const float*)d_in[4];
  const float* bk = (const float*)d_in[5];
  const float* Wv = (const float*)d_in[6];
  const float* bv = (const float*)d_in[7];
  const float* Wq = (const float*)d_in[8];
  const float* bq = (const float*)d_in[9];
  const float* Wo = (const float*)d_in[10];
  const float* bo = (const float*)d_in[11];

  char* ws = (char*)d_ws;  // needs ~75.6 MB
  u16* WtK = (u16*)(ws);
  u16* WtV = (u16*)(ws + (2u << 20));
  u16* WtQ = (u16*)(ws + (4u << 20));
  u16* WtO = (u16*)(ws + (6u << 20));
  u16* Kup = (u16*)(ws + (8u << 20));   // [b][h][l][dh] bf16
  u16* Qup = (u16*)(ws + (24u << 20));  // [b][h][l][dh] bf16
  u16* Vt  = (u16*)(ws + (40u << 20));  // [b][h][dh][l] bf16
  u16* ctx = (u16*)(ws + (56u << 20));  // [b][l][1024] bf16
  float2* stats = (float2*)(ws + (72u << 20));  // [b*2048] (m_log2, lsum)

  wtrans4_k<<<dim3(16, 16, 4), 256, 0, stream>>>(Wk, Wv, Wq, Wo, WtK, WtV,
                                                 WtQ, WtO);

  // Q scale folds 1/sqrt(DH) and log2(e) so softmax runs on exp2 directly.
  const float qscale = 0.125f * 1.44269504088896340736f;
  qkvgemm_k<<<dim3(512, 1, 3), 256, 0, stream>>>(
      key, value, query, WtK, WtV, WtQ, bk, bv, bq, Kup, Vt, Qup, qscale);

  attn_k<<<dim3(64, 16), 512, 0, stream>>>(Qup, Kup, Vt, ctx, stats);

  float* out = (float*)d_out;
  probs_k<<<dim3(16, 32, 4), 256, 0, stream>>>(Qup, Kup, stats,
                                               out + (size_t)8388608);

  outgemm_k<<<512, 256, 0, stream>>>(ctx, WtO, bo, out);
}

// Round 7
// 238.485 us; speedup vs baseline: 1.6464x; 1.0464x over previous
//
#include <hip/hip_runtime.h>
#include <hip/hip_bf16.h>
#include <stdint.h>

typedef unsigned short u16;
typedef unsigned int u32;
typedef __attribute__((ext_vector_type(8))) short bf16x8;
typedef __attribute__((ext_vector_type(4))) float f32x4;
typedef __attribute__((address_space(1))) unsigned int as1u;
typedef __attribute__((address_space(3))) unsigned int as3u;

#define DEV __device__ __forceinline__

DEV u16 f2bf(float f) {
  union { float f; unsigned u; } v; v.f = f;
  unsigned r = v.u + 0x7FFFu + ((v.u >> 16) & 1u);  // RNE
  return (u16)(r >> 16);
}

// hardware packed fp32->bf16 convert (no builtin on gfx950)
DEV u32 cvtpk(float lo, float hi) {
  u32 r;
  asm("v_cvt_pk_bf16_f32 %0, %1, %2" : "=v"(r) : "v"(lo), "v"(hi));
  return r;
}

DEV void gl_lds16(const void* g, void* l) {
  __builtin_amdgcn_global_load_lds(
      reinterpret_cast<as1u*>(reinterpret_cast<uintptr_t>(g)),
      reinterpret_cast<as3u*>(reinterpret_cast<uintptr_t>(l)), 16, 0, 0);
}

// XOR-swizzled index helpers. Tiles are [rows][64] elements.
DEV int swzh(int r, int c) { return r * 64 + (c ^ ((r & 7) << 3)); }
DEV int swzf(int r, int c) { return r * 64 + (c ^ ((r & 7) << 2)); }

// XCD swizzle for 512-block GEMM grids: launched bids {x, x+8, x+16, ...}
// (same XCD under round-robin) map to contiguous work ids -> the 8 col-blocks
// of each 128-row A panel share one XCD's L2.
DEV int xcdswz512(int bid) { return ((bid & 7) << 6) | (bid >> 3); }

// ---------------- fp32 -> bf16 streaming convert (3 tensors via z) ---------
__global__ __launch_bounds__(256) void cvt3_k(const float* __restrict__ I0,
                                              const float* __restrict__ I1,
                                              const float* __restrict__ I2,
                                              u16* __restrict__ O0,
                                              u16* __restrict__ O1,
                                              u16* __restrict__ O2) {
  const int z = blockIdx.z;
  const float* in = z == 0 ? I0 : z == 1 ? I1 : I2;
  u16* out = z == 0 ? O0 : z == 1 ? O1 : O2;
  const int idx = blockIdx.x * 256 + threadIdx.x;  // 262144 threads
#pragma unroll
  for (int j = 0; j < 8; ++j) {
    const int i = j * 262144 + idx;  // float4 index, 2.1M total
    float4 x = ((const float4*)in)[i];
    uint2 p;
    p.x = cvtpk(x.x, x.y);
    p.y = cvtpk(x.z, x.w);
    ((uint2*)out)[i] = p;
  }
}

// ---------------- weight transpose+convert (all 4 weights, z-indexed) ------
__global__ __launch_bounds__(256) void wtrans4_k(
    const float* __restrict__ W0, const float* __restrict__ W1,
    const float* __restrict__ W2, const float* __restrict__ W3,
    u16* __restrict__ T0, u16* __restrict__ T1, u16* __restrict__ T2,
    u16* __restrict__ T3) {
  const int z = blockIdx.z;
  const float* W = z == 0 ? W0 : z == 1 ? W1 : z == 2 ? W2 : W3;
  u16* Wt = z == 0 ? T0 : z == 1 ? T1 : z == 2 ? T2 : T3;
  __shared__ float t[64][65];
  const int tid = threadIdx.x;
  const int n0 = blockIdx.x * 64, k0 = blockIdx.y * 64;
  const int c = tid & 63, r4 = tid >> 6;
#pragma unroll
  for (int i = 0; i < 16; ++i) {
    int r = r4 * 16 + i;
    t[r][c] = W[(size_t)(k0 + r) * 1024 + n0 + c];
  }
  __syncthreads();
#pragma unroll
  for (int i = 0; i < 16; ++i) {
    int r = r4 * 16 + i;
    Wt[(size_t)(n0 + r) * 1024 + k0 + c] = f2bf(t[c][r]);
  }
}

// ---------------- fused QKV projection GEMM (z = 0:K, 1:V, 2:Q) ------------
// ABF16: A bf16 [8192][1024] (preconverted). Else A fp32 (fallback).
// Bt bf16 [1024][1024]. z=1 writes V-transposed, else head-major.
template <bool ABF16>
__global__ __launch_bounds__(256) void qkvgemm_k(
    const void* __restrict__ Akey, const void* __restrict__ Aval,
    const void* __restrict__ Aqry, const u16* __restrict__ BtK,
    const u16* __restrict__ BtV, const u16* __restrict__ BtQ,
    const float* __restrict__ bk, const float* __restrict__ bv,
    const float* __restrict__ bq, u16* __restrict__ Kup, u16* __restrict__ Vt,
    u16* __restrict__ Qup, float qscale) {
  constexpr int K = 1024;
  const int z = blockIdx.z;
  const void* Ap = z == 0 ? Akey : z == 1 ? Aval : Aqry;
  const u16* Bt = z == 0 ? BtK : z == 1 ? BtV : BtQ;
  const float* bias = z == 0 ? bk : z == 1 ? bv : bq;
  u16* Cp = z == 0 ? Kup : z == 1 ? Vt : Qup;
  const float scale = z == 2 ? qscale : 1.0f;

  __shared__ alignas(16) char smem[ABF16 ? 32768 : 49152];
  u16* Bs = (u16*)(smem + (ABF16 ? 16384 : 32768));

  const int tid = threadIdx.x;
  const int lane = tid & 63, wid = tid >> 6;
  const int swz = xcdswz512(blockIdx.x);
  const int brow = (swz >> 3) * 128;
  const int bcol = (swz & 7) * 128;
  const int wr = (wid >> 1) * 64, wc = (wid & 1) * 64;

  f32x4 acc[4][4] = {};

  for (int kt = 0; kt < K; kt += 64) {
    __syncthreads();
    if constexpr (ABF16) {
      const u16* Ah = (const u16*)Ap;
#pragma unroll
      for (int i = 0; i < 4; ++i) {
        int row = i * 32 + (tid >> 3);
        gl_lds16(Ah + (size_t)(brow + row) * K + kt +
                     (((tid & 7) ^ (row & 7)) << 3),
                 smem + i * 4096 + wid * 1024);
      }
    } else {
      const float* Af = (const float*)Ap;
#pragma unroll
      for (int i = 0; i < 8; ++i) {
        int row = i * 16 + (tid >> 4);
        gl_lds16(Af + (size_t)(brow + row) * K + kt +
                     (((tid & 15) ^ (row & 7)) << 2),
                 smem + i * 4096 + wid * 1024);
      }
    }
#pragma unroll
    for (int i = 0; i < 4; ++i) {
      int row = i * 32 + (tid >> 3);
      gl_lds16(Bt + (size_t)(bcol + row) * K + kt +
                   (((tid & 7) ^ (row & 7)) << 3),
               (char*)Bs + i * 4096 + wid * 1024);
    }
    __syncthreads();

#pragma unroll
    for (int kk = 0; kk < 2; ++kk) {
      const int kcol = kk * 32 + (lane >> 4) * 8;
      bf16x8 a[4], bfr[4];
#pragma unroll
      for (int m = 0; m < 4; ++m) {
        const int row = wr + m * 16 + (lane & 15);
        if constexpr (ABF16) {
          a[m] = *(const bf16x8*)((u16*)smem + swzh(row, kcol));
        } else {
          float4 x0 = *(const float4*)((float*)smem + swzf(row, kcol));
          float4 x1 = *(const float4*)((float*)smem + swzf(row, kcol + 4));
          union { u32 w[4]; bf16x8 v; } u;
          u.w[0] = cvtpk(x0.x, x0.y);
          u.w[1] = cvtpk(x0.z, x0.w);
          u.w[2] = cvtpk(x1.x, x1.y);
          u.w[3] = cvtpk(x1.z, x1.w);
          a[m] = u.v;
        }
      }
#pragma unroll
      for (int n = 0; n < 4; ++n)
        bfr[n] = *(const bf16x8*)(Bs + swzh(wc + n * 16 + (lane & 15), kcol));
#pragma unroll
      for (int m = 0; m < 4; ++m)
#pragma unroll
        for (int n = 0; n < 4; ++n)
          acc[m][n] = __builtin_amdgcn_mfma_f32_16x16x32_bf16(
              a[m], bfr[n], acc[m][n], 0, 0, 0);
    }
  }

#pragma unroll
  for (int m = 0; m < 4; ++m) {
    const int row0 = brow + wr + m * 16 + ((lane >> 4) << 2);
#pragma unroll
    for (int n = 0; n < 4; ++n) {
      const int col = bcol + wc + n * 16 + (lane & 15);
      const float bv2 = bias[col];
#pragma unroll
      for (int r = 0; r < 4; ++r) {
        const int row = row0 + r;
        const float val = (acc[m][n][r] + bv2) * scale;
        const int b = row >> 11, l = row & 2047, h = col >> 6, dh = col & 63;
        if (z == 1)
          Cp[((size_t)((b << 4) + h) * 64 + dh) * 2048 + l] = f2bf(val);
        else
          Cp[((size_t)((b << 4) + h) * 2048 + l) * 64 + dh] = f2bf(val);
      }
    }
  }
}

// ---------------- output GEMM: C = ctx @ Wt^T + bias (fp32 out) ------------
__global__ __launch_bounds__(256) void outgemm_k(const u16* __restrict__ Ah,
                                                 const u16* __restrict__ Bt,
                                                 const float* __restrict__ bias,
                                                 float* __restrict__ Cp) {
  constexpr int K = 1024;
  __shared__ alignas(16) char smem[32768];
  u16* Ash = (u16*)smem;
  u16* Bs = (u16*)(smem + 16384);

  const int tid = threadIdx.x;
  const int lane = tid & 63, wid = tid >> 6;
  const int swz = xcdswz512(blockIdx.x);
  const int brow = (swz >> 3) * 128;
  const int bcol = (swz & 7) * 128;
  const int wr = (wid >> 1) * 64, wc = (wid & 1) * 64;

  f32x4 acc[4][4] = {};

  for (int kt = 0; kt < K; kt += 64) {
    __syncthreads();
#pragma unroll
    for (int i = 0; i < 4; ++i) {
      int row = i * 32 + (tid >> 3);
      gl_lds16(Ah + (size_t)(brow + row) * K + kt +
                   (((tid & 7) ^ (row & 7)) << 3),
               smem + i * 4096 + wid * 1024);
      gl_lds16(Bt + (size_t)(bcol + row) * K + kt +
                   (((tid & 7) ^ (row & 7)) << 3),
               (char*)Bs + i * 4096 + wid * 1024);
    }
    __syncthreads();

#pragma unroll
    for (int kk = 0; kk < 2; ++kk) {
      const int kcol = kk * 32 + (lane >> 4) * 8;
      bf16x8 a[4], bfr[4];
#pragma unroll
      for (int m = 0; m < 4; ++m)
        a[m] = *(const bf16x8*)(Ash + swzh(wr + m * 16 + (lane & 15), kcol));
#pragma unroll
      for (int n = 0; n < 4; ++n)
        bfr[n] = *(const bf16x8*)(Bs + swzh(wc + n * 16 + (lane & 15), kcol));
#pragma unroll
      for (int m = 0; m < 4; ++m)
#pragma unroll
        for (int n = 0; n < 4; ++n)
          acc[m][n] = __builtin_amdgcn_mfma_f32_16x16x32_bf16(
              a[m], bfr[n], acc[m][n], 0, 0, 0);
    }
  }

#pragma unroll
  for (int m = 0; m < 4; ++m) {
    const int row0 = brow + wr + m * 16 + ((lane >> 4) << 2);
#pragma unroll
    for (int n = 0; n < 4; ++n) {
      const int col = bcol + wc + n * 16 + (lane & 15);
      const float bv2 = bias[col];
#pragma unroll
      for (int r = 0; r < 4; ++r)
        Cp[(size_t)(row0 + r) * 1024 + col] = acc[m][n][r] + bv2;
    }
  }
}

// ---------------- flash attention: 8 waves, 128-row Q tile -----------------
// Q,K: bf16 [bh][l][64] (Q pre-scaled by 0.125*log2e); Vt: bf16 [bh][64][l]
// K,V double-buffered; stage(kt+1) at top, compute on previous tile, one
// __syncthreads per iter. Mask gate tests wave's MIN q row (R5 fix).
__global__ __launch_bounds__(512, 6) void attn_k(const u16* __restrict__ Q,
                                                 const u16* __restrict__ K,
                                                 const u16* __restrict__ Vt,
                                                 u16* __restrict__ ctx,
                                                 float2* __restrict__ stats) {
  const int tid = threadIdx.x, lane = tid & 63, wid = tid >> 6;
  const int bh = blockIdx.x;
  const int qt = (int)(gridDim.y - 1) - (int)blockIdx.y;  // heavy blocks first
  const int b = bh >> 4, h = bh & 15;
  const size_t base = (size_t)bh * 2048 * 64;

  __shared__ alignas(16) u16 Ks[2][4096], Vs[2][4096], Ps[8192];

  bf16x8 qf[2];
  {
    const u16* qp = Q + base +
                    (size_t)(qt * 128 + wid * 16 + (lane & 15)) * 64 +
                    ((lane >> 4) << 3);
    qf[0] = *(const bf16x8*)(qp);
    qf[1] = *(const bf16x8*)(qp + 32);
  }

  const int srow = tid >> 3;                        // 0..63
  const int scol = ((tid & 7) ^ (srow & 7)) << 3;   // pre-swizzled src col

  f32x4 acc_o[4] = {};
  float m_run = -1e30f, l_run = 0.f;
  const int q = qt * 128 + wid * 16 + (lane & 15);
  const int qminw = qt * 128 + wid * 16;
  const int qmaxw = qminw + 15;
  const int g = lane >> 4;
  const int rmask7 = lane & 7;

  const int NT = 2 * qt + 2;

  gl_lds16(K + base + (size_t)srow * 64 + scol, (char*)Ks + tid * 16);
  gl_lds16(Vt + base + (size_t)srow * 2048 + scol, (char*)Vs + tid * 16);
  __syncthreads();

  int cur = 0;
  for (int kt = 0; kt < NT; ++kt) {
    if (kt < NT - 1) {
      gl_lds16(K + base + (size_t)((kt + 1) * 64 + srow) * 64 + scol,
               (char*)Ks + (cur ^ 1) * 8192 + tid * 16);
      gl_lds16(Vt + base + (size_t)srow * 2048 + (kt + 1) * 64 + scol,
               (char*)Vs + (cur ^ 1) * 8192 + tid * 16);
    }

    if (kt * 64 <= qmaxw) {
      f32x4 s[4] = {};
#pragma unroll
      for (int kk = 0; kk < 2; ++kk) {
        const int kcb = kk * 64 + g * 16;
#pragma unroll
        for (int n = 0; n < 4; ++n) {
          const int row = n * 16 + (lane & 15);
          bf16x8 kf = *(const bf16x8*)((char*)Ks + cur * 8192 + row * 128 +
                                       (kcb ^ (rmask7 << 4)));
          s[n] = __builtin_amdgcn_mfma_f32_16x16x32_bf16(kf, qf[kk], s[n],
                                                         0, 0, 0);
        }
      }

      if (kt * 64 + 63 > qminw) {  // mask kv > q (gate on MIN row)
        const int kb = kt * 64 + g * 4;
#pragma unroll
        for (int n = 0; n < 4; ++n)
#pragma unroll
          for (int r = 0; r < 4; ++r)
            if (kb + n * 16 + r > q) s[n][r] = -1e30f;
      }

      float mx = s[0][0];
#pragma unroll
      for (int n = 0; n < 4; ++n)
#pragma unroll
        for (int r = 0; r < 4; ++r) mx = fmaxf(mx, s[n][r]);
      mx = fmaxf(mx, __shfl_xor(mx, 16, 64));
      mx = fmaxf(mx, __shfl_xor(mx, 32, 64));

      if (__any(mx - m_run > 8.0f)) {  // defer-max (log2 units)
        const float mn = fmaxf(m_run, mx);
        const float alpha = exp2f(m_run - mn);
        m_run = mn;
        l_run *= alpha;
#pragma unroll
        for (int r = 0; r < 4; ++r) {
          const float ar = __shfl(alpha, (g << 2) + r, 64);
#pragma unroll
          for (int n = 0; n < 4; ++n) acc_o[n][r] *= ar;
        }
      }

      float rs = 0.f;
#pragma unroll
      for (int n = 0; n < 4; ++n)
#pragma unroll
        for (int r = 0; r < 4; ++r) {
          const float pv = exp2f(s[n][r] - m_run);
          s[n][r] = pv;
          rs += pv;
        }
      rs += __shfl_xor(rs, 16, 64);
      rs += __shfl_xor(rs, 32, 64);
      l_run += rs;

#pragma unroll
      for (int n = 0; n < 4; ++n) {
        union { u32 w[2]; uint2 u; } pk;
        pk.w[0] = cvtpk(s[n][0], s[n][1]);
        pk.w[1] = cvtpk(s[n][2], s[n][3]);
        *(uint2*)((char*)Ps + wid * 2048 + (lane & 15) * 128 +
                  ((n * 32 + g * 8) ^ (rmask7 << 4))) = pk.u;
      }
      asm volatile("s_waitcnt lgkmcnt(0)" ::: "memory");

#pragma unroll
      for (int kk = 0; kk < 2; ++kk) {
        const int kcb = kk * 64 + g * 16;
        bf16x8 pf = *(const bf16x8*)((char*)Ps + wid * 2048 +
                                     (lane & 15) * 128 + (kcb ^ (rmask7 << 4)));
#pragma unroll
        for (int n = 0; n < 4; ++n) {
          const int row = n * 16 + (lane & 15);
          bf16x8 vf = *(const bf16x8*)((char*)Vs + cur * 8192 + row * 128 +
                                       (kcb ^ (rmask7 << 4)));
          acc_o[n] = __builtin_amdgcn_mfma_f32_16x16x32_bf16(pf, vf, acc_o[n],
                                                             0, 0, 0);
        }
      }
    }
    __syncthreads();
    cur ^= 1;
  }

  float linv[4];
#pragma unroll
  for (int r = 0; r < 4; ++r)
    linv[r] = 1.0f / __shfl(l_run, (g << 2) + r, 64);
#pragma unroll
  for (int r = 0; r < 4; ++r) {
    const int qo = qt * 128 + wid * 16 + (g << 2) + r;
#pragma unroll
    for (int n = 0; n < 4; ++n) {
      const int dh = n * 16 + (lane & 15);
      ctx[((size_t)(b * 2048 + qo)) * 1024 + h * 64 + dh] =
          f2bf(acc_o[n][r] * linv[r]);
    }
  }
  if (h == 0 && g == 0)
    stats[b * 2048 + q] = make_float2(m_run, l_run);
}

// ---------------- top_attn (head 0) probabilities -------------------------
__global__ __launch_bounds__(256) void probs_k(const u16* __restrict__ Q,
                                               const u16* __restrict__ K,
                                               const float2* __restrict__ stats,
                                               float* __restrict__ out) {
  const int tid = threadIdx.x, lane = tid & 63, wid = tid >> 6;
  const int kt2 = blockIdx.x, qt = blockIdx.y, b = blockIdx.z;
  const int q0 = qt * 64, c0 = kt2 * 128;
  float* ot = out + ((size_t)b * 2048 + q0) * 2048 + c0;

  if (c0 > q0 + 63) {  // whole tile masked -> zero-fill
    const float4 z = make_float4(0.f, 0.f, 0.f, 0.f);
#pragma unroll
    for (int i = 0; i < 8; ++i) {
      const int idx = i * 256 + tid;
      *(float4*)(ot + (size_t)(idx >> 5) * 2048 + ((idx & 31) << 2)) = z;
    }
    return;
  }

  __shared__ alignas(16) u16 Qs[4096], Ks2[8192];
  const size_t base = (size_t)(b * 16) * 2048 * 64;  // h = 0
#pragma unroll
  for (int i = 0; i < 2; ++i) {
    int row = i * 32 + (tid >> 3);
    gl_lds16(Q + base + (size_t)(q0 + row) * 64 + (((tid & 7) ^ (row & 7)) << 3),
             (char*)Qs + i * 4096 + wid * 1024);
  }
#pragma unroll
  for (int i = 0; i < 4; ++i) {
    int row = i * 32 + (tid >> 3);
    gl_lds16(K + base + (size_t)(c0 + row) * 64 + (((tid & 7) ^ (row & 7)) << 3),
             (char*)Ks2 + i * 4096 + wid * 1024);
  }
  __syncthreads();

  f32x4 s[8] = {};
#pragma unroll
  for (int kk = 0; kk < 2; ++kk) {
    const int kc = kk * 32 + (lane >> 4) * 8;
    bf16x8 aq = *(const bf16x8*)(Qs + swzh(wid * 16 + (lane & 15), kc));
#pragma unroll
    for (int n = 0; n < 8; ++n) {
      bf16x8 bk = *(const bf16x8*)(Ks2 + swzh(n * 16 + (lane & 15), kc));
      s[n] = __builtin_amdgcn_mfma_f32_16x16x32_bf16(aq, bk, s[n], 0, 0, 0);
    }
  }

#pragma unroll
  for (int r = 0; r < 4; ++r) {
    const int q = q0 + wid * 16 + ((lane >> 4) << 2) + r;
    const float2 st = stats[b * 2048 + q];
    const float rl = 1.0f / st.y;
#pragma unroll
    for (int n = 0; n < 8; ++n) {
      const int kp = c0 + n * 16 + (lane & 15);
      out[((size_t)b * 2048 + q) * 2048 + kp] =
          (kp <= q) ? exp2f(s[n][r] - st.x) * rl : 0.f;
    }
  }
}

extern "C" void kernel_launch(void* const* d_in, const int* in_sizes, int n_in,
                              void* d_out, int out_size, void* d_ws,
                              size_t ws_size, hipStream_t stream) {
  (void)in_sizes; (void)n_in; (void)out_size;
  const float* key = (const float*)d_in[0];
  const float* value = (const float*)d_in[1];
  const float* query = (const float*)d_in[2];
  const float* Wk = (const float*)d_in[4];
  const float* bk = (const float*)d_in[5];
  const float* Wv = (const float*)d_in[6];
  const float* bv = (const float*)d_in[7];
  const float* Wq = (const float*)d_in[8];
  const float* bq = (const float*)d_in[9];
  const float* Wo = (const float*)d_in[10];
  const float* bo = (const float*)d_in[11];

  char* ws = (char*)d_ws;
  u16* WtK = (u16*)(ws);
  u16* WtV = (u16*)(ws + (2u << 20));
  u16* WtQ = (u16*)(ws + (4u << 20));
  u16* WtO = (u16*)(ws + (6u << 20));
  u16* Kup = (u16*)(ws + (8u << 20));   // [b][h][l][dh] bf16
  u16* Qup = (u16*)(ws + (24u << 20));  // [b][h][l][dh] bf16
  u16* Vt  = (u16*)(ws + (40u << 20));  // [b][h][dh][l] bf16
  u16* ctx = (u16*)(ws + (56u << 20));  // [b][l][1024] bf16
  float2* stats = (float2*)(ws + (72u << 20));  // [b*2048] (m_log2, lsum)
  u16* Akb = (u16*)(ws + (76u << 20));  // bf16 key   [8192][1024]
  u16* Avb = (u16*)(ws + (92u << 20));  // bf16 value
  u16* Aqb = (u16*)(ws + (108u << 20)); // bf16 query
  const bool bf16path = ws_size >= ((size_t)124u << 20);

  wtrans4_k<<<dim3(16, 16, 4), 256, 0, stream>>>(Wk, Wv, Wq, Wo, WtK, WtV,
                                                 WtQ, WtO);

  // Q scale folds 1/sqrt(DH) and log2(e) so softmax runs on exp2 directly.
  const float qscale = 0.125f * 1.44269504088896340736f;
  if (bf16path) {
    cvt3_k<<<dim3(1024, 1, 3), 256, 0, stream>>>(key, value, query, Akb, Avb,
                                                 Aqb);
    qkvgemm_k<true><<<dim3(512, 1, 3), 256, 0, stream>>>(
        Akb, Avb, Aqb, WtK, WtV, WtQ, bk, bv, bq, Kup, Vt, Qup, qscale);
  } else {
    qkvgemm_k<false><<<dim3(512, 1, 3), 256, 0, stream>>>(
        key, value, query, WtK, WtV, WtQ, bk, bv, bq, Kup, Vt, Qup, qscale);
  }

  attn_k<<<dim3(64, 16), 512, 0, stream>>>(Qup, Kup, Vt, ctx, stats);

  float* out = (float*)d_out;
  probs_k<<<dim3(16, 32, 4), 256, 0, stream>>>(Qup, Kup, stats,
                                               out + (size_t)8388608);

  outgemm_k<<<512, 256, 0, stream>>>(ctx, WtO, bo, out);
}

// Round 8
// 206.308 us; speedup vs baseline: 1.9032x; 1.1560x over previous
//
#include <hip/hip_runtime.h>
#include <hip/hip_bf16.h>
#include <stdint.h>

typedef unsigned short u16;
typedef unsigned int u32;
typedef __attribute__((ext_vector_type(8))) short bf16x8;
typedef __attribute__((ext_vector_type(4))) float f32x4;
typedef __attribute__((address_space(1))) unsigned int as1u;
typedef __attribute__((address_space(3))) unsigned int as3u;

#define DEV __device__ __forceinline__

DEV u16 f2bf(float f) {
  union { float f; unsigned u; } v; v.f = f;
  unsigned r = v.u + 0x7FFFu + ((v.u >> 16) & 1u);  // RNE
  return (u16)(r >> 16);
}

// hardware packed fp32->bf16 convert (no builtin on gfx950)
DEV u32 cvtpk(float lo, float hi) {
  u32 r;
  asm("v_cvt_pk_bf16_f32 %0, %1, %2" : "=v"(r) : "v"(lo), "v"(hi));
  return r;
}

DEV void gl_lds16(const void* g, void* l) {
  __builtin_amdgcn_global_load_lds(
      reinterpret_cast<as1u*>(reinterpret_cast<uintptr_t>(g)),
      reinterpret_cast<as3u*>(reinterpret_cast<uintptr_t>(l)), 16, 0, 0);
}

// XOR-swizzled index helpers. Tiles are [rows][64] elements.
DEV int swzh(int r, int c) { return r * 64 + (c ^ ((r & 7) << 3)); }
DEV int swzf(int r, int c) { return r * 64 + (c ^ ((r & 7) << 2)); }

// XCD swizzle for 512-block GEMM grids: the 8 col-blocks of each 128-row A
// panel land on one XCD's L2.
DEV int xcdswz512(int bid) { return ((bid & 7) << 6) | (bid >> 3); }

// ---------------- fp32 -> bf16 streaming convert (3 tensors via z) ---------
__global__ __launch_bounds__(256) void cvt3_k(const float* __restrict__ I0,
                                              const float* __restrict__ I1,
                                              const float* __restrict__ I2,
                                              u16* __restrict__ O0,
                                              u16* __restrict__ O1,
                                              u16* __restrict__ O2) {
  const int z = blockIdx.z;
  const float* in = z == 0 ? I0 : z == 1 ? I1 : I2;
  u16* out = z == 0 ? O0 : z == 1 ? O1 : O2;
  const int idx = blockIdx.x * 256 + threadIdx.x;  // 262144 threads
#pragma unroll
  for (int j = 0; j < 8; ++j) {
    const int i = j * 262144 + idx;  // float4 index, 2.1M total
    float4 x = ((const float4*)in)[i];
    uint2 p;
    p.x = cvtpk(x.x, x.y);
    p.y = cvtpk(x.z, x.w);
    ((uint2*)out)[i] = p;
  }
}

// ---------------- weight transpose+convert (all 4 weights, z-indexed) ------
__global__ __launch_bounds__(256) void wtrans4_k(
    const float* __restrict__ W0, const float* __restrict__ W1,
    const float* __restrict__ W2, const float* __restrict__ W3,
    u16* __restrict__ T0, u16* __restrict__ T1, u16* __restrict__ T2,
    u16* __restrict__ T3) {
  const int z = blockIdx.z;
  const float* W = z == 0 ? W0 : z == 1 ? W1 : z == 2 ? W2 : W3;
  u16* Wt = z == 0 ? T0 : z == 1 ? T1 : z == 2 ? T2 : T3;
  __shared__ float t[64][65];
  const int tid = threadIdx.x;
  const int n0 = blockIdx.x * 64, k0 = blockIdx.y * 64;
  const int c = tid & 63, r4 = tid >> 6;
#pragma unroll
  for (int i = 0; i < 16; ++i) {
    int r = r4 * 16 + i;
    t[r][c] = W[(size_t)(k0 + r) * 1024 + n0 + c];
  }
  __syncthreads();
#pragma unroll
  for (int i = 0; i < 16; ++i) {
    int r = r4 * 16 + i;
    Wt[(size_t)(n0 + r) * 1024 + k0 + c] = f2bf(t[c][r]);
  }
}

// ---------------- fused QKV projection GEMM, bf16 A, T3-min dbuf -----------
// A bf16 [8192][1024]; Bt bf16 [1024][1024]. z=0:K, 1:V(transposed out), 2:Q.
// Double-buffered LDS, ONE barrier per K-step (stage(t+1) -> compute(t) ->
// barrier; the barrier's implicit vmcnt(0) drain publishes the prefetch).
__global__ __launch_bounds__(256) void qkvgemm_k(
    const u16* __restrict__ Akey, const u16* __restrict__ Aval,
    const u16* __restrict__ Aqry, const u16* __restrict__ BtK,
    const u16* __restrict__ BtV, const u16* __restrict__ BtQ,
    const float* __restrict__ bk, const float* __restrict__ bv,
    const float* __restrict__ bq, u16* __restrict__ Kup, u16* __restrict__ Vt,
    u16* __restrict__ Qup, float qscale) {
  constexpr int K = 1024;
  const int z = blockIdx.z;
  const u16* Ah = z == 0 ? Akey : z == 1 ? Aval : Aqry;
  const u16* Bt = z == 0 ? BtK : z == 1 ? BtV : BtQ;
  const float* bias = z == 0 ? bk : z == 1 ? bv : bq;
  u16* Cp = z == 0 ? Kup : z == 1 ? Vt : Qup;
  const float scale = z == 2 ? qscale : 1.0f;

  __shared__ alignas(16) char smem[65536];  // [buf][A 16K | B 16K]

  const int tid = threadIdx.x;
  const int lane = tid & 63, wid = tid >> 6;
  const int swz = xcdswz512(blockIdx.x);
  const int brow = (swz >> 3) * 128;
  const int bcol = (swz & 7) * 128;
  const int wr = (wid >> 1) * 64, wc = (wid & 1) * 64;

  f32x4 acc[4][4] = {};

  auto stage = [&](int kt, int buf) {
#pragma unroll
    for (int i = 0; i < 4; ++i) {
      int row = i * 32 + (tid >> 3);
      const int sc = ((tid & 7) ^ (row & 7)) << 3;
      gl_lds16(Ah + (size_t)(brow + row) * K + kt + sc,
               smem + buf * 32768 + i * 4096 + wid * 1024);
      gl_lds16(Bt + (size_t)(bcol + row) * K + kt + sc,
               smem + buf * 32768 + 16384 + i * 4096 + wid * 1024);
    }
  };

  stage(0, 0);
  __syncthreads();

  int cur = 0;
  for (int kt = 0; kt < K; kt += 64) {
    if (kt + 64 < K) stage(kt + 64, cur ^ 1);
    const u16* Ash = (const u16*)(smem + cur * 32768);
    const u16* Bs = (const u16*)(smem + cur * 32768 + 16384);
#pragma unroll
    for (int kk = 0; kk < 2; ++kk) {
      const int kcol = kk * 32 + (lane >> 4) * 8;
      bf16x8 a[4], bfr[4];
#pragma unroll
      for (int m = 0; m < 4; ++m)
        a[m] = *(const bf16x8*)(Ash + swzh(wr + m * 16 + (lane & 15), kcol));
#pragma unroll
      for (int n = 0; n < 4; ++n)
        bfr[n] = *(const bf16x8*)(Bs + swzh(wc + n * 16 + (lane & 15), kcol));
#pragma unroll
      for (int m = 0; m < 4; ++m)
#pragma unroll
        for (int n = 0; n < 4; ++n)
          acc[m][n] = __builtin_amdgcn_mfma_f32_16x16x32_bf16(
              a[m], bfr[n], acc[m][n], 0, 0, 0);
    }
    __syncthreads();
    cur ^= 1;
  }
  // all waves past final barrier: LDS free for epilogue reuse

  const int g = lane >> 4;
  if (z == 1) {
    // V: LDS transpose -> coalesced stores along l (fixes 2B-scatter)
    u16* T = (u16*)smem;  // [dh_local 128][l_local 128] bf16, swizzled
#pragma unroll
    for (int m = 0; m < 4; ++m) {
      const int row0 = wr + m * 16 + g * 4;  // l_local
#pragma unroll
      for (int n = 0; n < 4; ++n) {
        const int col = wc + n * 16 + (lane & 15);  // dh_local
        const float bv2 = bias[bcol + col];
        uint2 p;
        p.x = cvtpk(acc[m][n][0] + bv2, acc[m][n][1] + bv2);
        p.y = cvtpk(acc[m][n][2] + bv2, acc[m][n][3] + bv2);
        *(uint2*)((char*)T + col * 256 + ((row0 * 2) ^ ((col & 7) << 4))) = p;
      }
    }
    __syncthreads();
    const int bI = brow >> 11, l0 = brow & 2047;
#pragma unroll
    for (int i = 0; i < 8; ++i) {
      const int rr = i * 16 + (tid >> 4);  // dh_local 0..127
      const int xb = (tid & 15) * 16;      // byte offset in row (l*2)
      uint4 v = *(uint4*)((char*)T + rr * 256 + (xb ^ ((rr & 7) << 4)));
      const int colg = bcol + rr;
      const int hh = colg >> 6, dh = colg & 63;
      *(uint4*)(&Cp[((size_t)((bI << 4) + hh) * 64 + dh) * 2048 + l0 +
                    (xb >> 1)]) = v;
    }
  } else {
    // K / Q: head-major stores (coalesced 32B per 16-lane group)
#pragma unroll
    for (int m = 0; m < 4; ++m) {
      const int row0 = brow + wr + m * 16 + (g << 2);
#pragma unroll
      for (int n = 0; n < 4; ++n) {
        const int col = bcol + wc + n * 16 + (lane & 15);
        const float bv2 = bias[col];
        const int h = col >> 6, dh = col & 63;
#pragma unroll
        for (int r = 0; r < 4; ++r) {
          const int row = row0 + r;
          const float val = (acc[m][n][r] + bv2) * scale;
          const int b = row >> 11, l = row & 2047;
          Cp[((size_t)((b << 4) + h) * 2048 + l) * 64 + dh] = f2bf(val);
        }
      }
    }
  }
}

// ---------------- output GEMM: C = ctx @ Wt^T + bias (fp32 out), dbuf ------
__global__ __launch_bounds__(256) void outgemm_k(const u16* __restrict__ Ah,
                                                 const u16* __restrict__ Bt,
                                                 const float* __restrict__ bias,
                                                 float* __restrict__ Cp) {
  constexpr int K = 1024;
  __shared__ alignas(16) char smem[65536];

  const int tid = threadIdx.x;
  const int lane = tid & 63, wid = tid >> 6;
  const int swz = xcdswz512(blockIdx.x);
  const int brow = (swz >> 3) * 128;
  const int bcol = (swz & 7) * 128;
  const int wr = (wid >> 1) * 64, wc = (wid & 1) * 64;

  f32x4 acc[4][4] = {};

  auto stage = [&](int kt, int buf) {
#pragma unroll
    for (int i = 0; i < 4; ++i) {
      int row = i * 32 + (tid >> 3);
      const int sc = ((tid & 7) ^ (row & 7)) << 3;
      gl_lds16(Ah + (size_t)(brow + row) * K + kt + sc,
               smem + buf * 32768 + i * 4096 + wid * 1024);
      gl_lds16(Bt + (size_t)(bcol + row) * K + kt + sc,
               smem + buf * 32768 + 16384 + i * 4096 + wid * 1024);
    }
  };

  stage(0, 0);
  __syncthreads();

  int cur = 0;
  for (int kt = 0; kt < K; kt += 64) {
    if (kt + 64 < K) stage(kt + 64, cur ^ 1);
    const u16* Ash = (const u16*)(smem + cur * 32768);
    const u16* Bs = (const u16*)(smem + cur * 32768 + 16384);
#pragma unroll
    for (int kk = 0; kk < 2; ++kk) {
      const int kcol = kk * 32 + (lane >> 4) * 8;
      bf16x8 a[4], bfr[4];
#pragma unroll
      for (int m = 0; m < 4; ++m)
        a[m] = *(const bf16x8*)(Ash + swzh(wr + m * 16 + (lane & 15), kcol));
#pragma unroll
      for (int n = 0; n < 4; ++n)
        bfr[n] = *(const bf16x8*)(Bs + swzh(wc + n * 16 + (lane & 15), kcol));
#pragma unroll
      for (int m = 0; m < 4; ++m)
#pragma unroll
        for (int n = 0; n < 4; ++n)
          acc[m][n] = __builtin_amdgcn_mfma_f32_16x16x32_bf16(
              a[m], bfr[n], acc[m][n], 0, 0, 0);
    }
    __syncthreads();
    cur ^= 1;
  }

#pragma unroll
  for (int m = 0; m < 4; ++m) {
    const int row0 = brow + wr + m * 16 + ((lane >> 4) << 2);
#pragma unroll
    for (int n = 0; n < 4; ++n) {
      const int col = bcol + wc + n * 16 + (lane & 15);
      const float bv2 = bias[col];
#pragma unroll
      for (int r = 0; r < 4; ++r)
        Cp[(size_t)(row0 + r) * 1024 + col] = acc[m][n][r] + bv2;
    }
  }
}

// ---------------- flash attention: 8 waves, 128-row Q tile -----------------
// Q,K: bf16 [bh][l][64] (Q pre-scaled by 0.125*log2e); Vt: bf16 [bh][64][l]
// K,V double-buffered; stage(kt+1) at top, compute on previous tile, one
// __syncthreads per iter. Mask gate tests wave's MIN q row.
__global__ __launch_bounds__(512, 6) void attn_k(const u16* __restrict__ Q,
                                                 const u16* __restrict__ K,
                                                 const u16* __restrict__ Vt,
                                                 u16* __restrict__ ctx,
                                                 float2* __restrict__ stats) {
  const int tid = threadIdx.x, lane = tid & 63, wid = tid >> 6;
  const int bh = blockIdx.x;
  const int qt = (int)(gridDim.y - 1) - (int)blockIdx.y;  // heavy blocks first
  const int b = bh >> 4, h = bh & 15;
  const size_t base = (size_t)bh * 2048 * 64;

  __shared__ alignas(16) u16 Ks[2][4096], Vs[2][4096], Ps[8192];

  bf16x8 qf[2];
  {
    const u16* qp = Q + base +
                    (size_t)(qt * 128 + wid * 16 + (lane & 15)) * 64 +
                    ((lane >> 4) << 3);
    qf[0] = *(const bf16x8*)(qp);
    qf[1] = *(const bf16x8*)(qp + 32);
  }

  const int srow = tid >> 3;                        // 0..63
  const int scol = ((tid & 7) ^ (srow & 7)) << 3;   // pre-swizzled src col

  f32x4 acc_o[4] = {};
  float m_run = -1e30f, l_run = 0.f;
  const int q = qt * 128 + wid * 16 + (lane & 15);
  const int qminw = qt * 128 + wid * 16;
  const int qmaxw = qminw + 15;
  const int g = lane >> 4;
  const int rmask7 = lane & 7;

  const int NT = 2 * qt + 2;

  gl_lds16(K + base + (size_t)srow * 64 + scol, (char*)Ks + tid * 16);
  gl_lds16(Vt + base + (size_t)srow * 2048 + scol, (char*)Vs + tid * 16);
  __syncthreads();

  int cur = 0;
  for (int kt = 0; kt < NT; ++kt) {
    if (kt < NT - 1) {
      gl_lds16(K + base + (size_t)((kt + 1) * 64 + srow) * 64 + scol,
               (char*)Ks + (cur ^ 1) * 8192 + tid * 16);
      gl_lds16(Vt + base + (size_t)srow * 2048 + (kt + 1) * 64 + scol,
               (char*)Vs + (cur ^ 1) * 8192 + tid * 16);
    }

    if (kt * 64 <= qmaxw) {
      f32x4 s[4] = {};
#pragma unroll
      for (int kk = 0; kk < 2; ++kk) {
        const int kcb = kk * 64 + g * 16;
#pragma unroll
        for (int n = 0; n < 4; ++n) {
          const int row = n * 16 + (lane & 15);
          bf16x8 kf = *(const bf16x8*)((char*)Ks + cur * 8192 + row * 128 +
                                       (kcb ^ (rmask7 << 4)));
          s[n] = __builtin_amdgcn_mfma_f32_16x16x32_bf16(kf, qf[kk], s[n],
                                                         0, 0, 0);
        }
      }

      if (kt * 64 + 63 > qminw) {  // mask kv > q (gate on MIN row)
        const int kb = kt * 64 + g * 4;
#pragma unroll
        for (int n = 0; n < 4; ++n)
#pragma unroll
          for (int r = 0; r < 4; ++r)
            if (kb + n * 16 + r > q) s[n][r] = -1e30f;
      }

      float mx = s[0][0];
#pragma unroll
      for (int n = 0; n < 4; ++n)
#pragma unroll
        for (int r = 0; r < 4; ++r) mx = fmaxf(mx, s[n][r]);
      mx = fmaxf(mx, __shfl_xor(mx, 16, 64));
      mx = fmaxf(mx, __shfl_xor(mx, 32, 64));

      if (__any(mx - m_run > 8.0f)) {  // defer-max (log2 units)
        const float mn = fmaxf(m_run, mx);
        const float alpha = exp2f(m_run - mn);
        m_run = mn;
        l_run *= alpha;
#pragma unroll
        for (int r = 0; r < 4; ++r) {
          const float ar = __shfl(alpha, (g << 2) + r, 64);
#pragma unroll
          for (int n = 0; n < 4; ++n) acc_o[n][r] *= ar;
        }
      }

      float rs = 0.f;
#pragma unroll
      for (int n = 0; n < 4; ++n)
#pragma unroll
        for (int r = 0; r < 4; ++r) {
          const float pv = exp2f(s[n][r] - m_run);
          s[n][r] = pv;
          rs += pv;
        }
      rs += __shfl_xor(rs, 16, 64);
      rs += __shfl_xor(rs, 32, 64);
      l_run += rs;

#pragma unroll
      for (int n = 0; n < 4; ++n) {
        union { u32 w[2]; uint2 u; } pk;
        pk.w[0] = cvtpk(s[n][0], s[n][1]);
        pk.w[1] = cvtpk(s[n][2], s[n][3]);
        *(uint2*)((char*)Ps + wid * 2048 + (lane & 15) * 128 +
                  ((n * 32 + g * 8) ^ (rmask7 << 4))) = pk.u;
      }
      asm volatile("s_waitcnt lgkmcnt(0)" ::: "memory");

#pragma unroll
      for (int kk = 0; kk < 2; ++kk) {
        const int kcb = kk * 64 + g * 16;
        bf16x8 pf = *(const bf16x8*)((char*)Ps + wid * 2048 +
                                     (lane & 15) * 128 + (kcb ^ (rmask7 << 4)));
#pragma unroll
        for (int n = 0; n < 4; ++n) {
          const int row = n * 16 + (lane & 15);
          bf16x8 vf = *(const bf16x8*)((char*)Vs + cur * 8192 + row * 128 +
                                       (kcb ^ (rmask7 << 4)));
          acc_o[n] = __builtin_amdgcn_mfma_f32_16x16x32_bf16(pf, vf, acc_o[n],
                                                             0, 0, 0);
        }
      }
    }
    __syncthreads();
    cur ^= 1;
  }

  float linv[4];
#pragma unroll
  for (int r = 0; r < 4; ++r)
    linv[r] = 1.0f / __shfl(l_run, (g << 2) + r, 64);
#pragma unroll
  for (int r = 0; r < 4; ++r) {
    const int qo = qt * 128 + wid * 16 + (g << 2) + r;
#pragma unroll
    for (int n = 0; n < 4; ++n) {
      const int dh = n * 16 + (lane & 15);
      ctx[((size_t)(b * 2048 + qo)) * 1024 + h * 64 + dh] =
          f2bf(acc_o[n][r] * linv[r]);
    }
  }
  if (h == 0 && g == 0)
    stats[b * 2048 + q] = make_float2(m_run, l_run);
}

// ---------------- top_attn (head 0) probabilities -------------------------
__global__ __launch_bounds__(256) void probs_k(const u16* __restrict__ Q,
                                               const u16* __restrict__ K,
                                               const float2* __restrict__ stats,
                                               float* __restrict__ out) {
  const int tid = threadIdx.x, lane = tid & 63, wid = tid >> 6;
  const int kt2 = blockIdx.x, qt = blockIdx.y, b = blockIdx.z;
  const int q0 = qt * 64, c0 = kt2 * 128;
  float* ot = out + ((size_t)b * 2048 + q0) * 2048 + c0;

  if (c0 > q0 + 63) {  // whole tile masked -> zero-fill
    const float4 z = make_float4(0.f, 0.f, 0.f, 0.f);
#pragma unroll
    for (int i = 0; i < 8; ++i) {
      const int idx = i * 256 + tid;
      *(float4*)(ot + (size_t)(idx >> 5) * 2048 + ((idx & 31) << 2)) = z;
    }
    return;
  }

  __shared__ alignas(16) u16 Qs[4096], Ks2[8192];
  const size_t base = (size_t)(b * 16) * 2048 * 64;  // h = 0
#pragma unroll
  for (int i = 0; i < 2; ++i) {
    int row = i * 32 + (tid >> 3);
    gl_lds16(Q + base + (size_t)(q0 + row) * 64 + (((tid & 7) ^ (row & 7)) << 3),
             (char*)Qs + i * 4096 + wid * 1024);
  }
#pragma unroll
  for (int i = 0; i < 4; ++i) {
    int row = i * 32 + (tid >> 3);
    gl_lds16(K + base + (size_t)(c0 + row) * 64 + (((tid & 7) ^ (row & 7)) << 3),
             (char*)Ks2 + i * 4096 + wid * 1024);
  }
  __syncthreads();

  f32x4 s[8] = {};
#pragma unroll
  for (int kk = 0; kk < 2; ++kk) {
    const int kc = kk * 32 + (lane >> 4) * 8;
    bf16x8 aq = *(const bf16x8*)(Qs + swzh(wid * 16 + (lane & 15), kc));
#pragma unroll
    for (int n = 0; n < 8; ++n) {
      bf16x8 bk = *(const bf16x8*)(Ks2 + swzh(n * 16 + (lane & 15), kc));
      s[n] = __builtin_amdgcn_mfma_f32_16x16x32_bf16(aq, bk, s[n], 0, 0, 0);
    }
  }

#pragma unroll
  for (int r = 0; r < 4; ++r) {
    const int q = q0 + wid * 16 + ((lane >> 4) << 2) + r;
    const float2 st = stats[b * 2048 + q];
    const float rl = 1.0f / st.y;
#pragma unroll
    for (int n = 0; n < 8; ++n) {
      const int kp = c0 + n * 16 + (lane & 15);
      out[((size_t)b * 2048 + q) * 2048 + kp] =
          (kp <= q) ? exp2f(s[n][r] - st.x) * rl : 0.f;
    }
  }
}

extern "C" void kernel_launch(void* const* d_in, const int* in_sizes, int n_in,
                              void* d_out, int out_size, void* d_ws,
                              size_t ws_size, hipStream_t stream) {
  (void)in_sizes; (void)n_in; (void)out_size; (void)ws_size;
  const float* key = (const float*)d_in[0];
  const float* value = (const float*)d_in[1];
  const float* query = (const float*)d_in[2];
  const float* Wk = (const float*)d_in[4];
  const float* bk = (const float*)d_in[5];
  const float* Wv = (const float*)d_in[6];
  const float* bv = (const float*)d_in[7];
  const float* Wq = (const float*)d_in[8];
  const float* bq = (const float*)d_in[9];
  const float* Wo = (const float*)d_in[10];
  const float* bo = (const float*)d_in[11];

  char* ws = (char*)d_ws;  // needs ~124 MB
  u16* WtK = (u16*)(ws);
  u16* WtV = (u16*)(ws + (2u << 20));
  u16* WtQ = (u16*)(ws + (4u << 20));
  u16* WtO = (u16*)(ws + (6u << 20));
  u16* Kup = (u16*)(ws + (8u << 20));   // [b][h][l][dh] bf16
  u16* Qup = (u16*)(ws + (24u << 20));  // [b][h][l][dh] bf16
  u16* Vt  = (u16*)(ws + (40u << 20));  // [b][h][dh][l] bf16
  u16* ctx = (u16*)(ws + (56u << 20));  // [b][l][1024] bf16
  float2* stats = (float2*)(ws + (72u << 20));  // [b*2048] (m_log2, lsum)
  u16* Akb = (u16*)(ws + (76u << 20));  // bf16 key   [8192][1024]
  u16* Avb = (u16*)(ws + (92u << 20));  // bf16 value
  u16* Aqb = (u16*)(ws + (108u << 20)); // bf16 query

  wtrans4_k<<<dim3(16, 16, 4), 256, 0, stream>>>(Wk, Wv, Wq, Wo, WtK, WtV,
                                                 WtQ, WtO);
  cvt3_k<<<dim3(1024, 1, 3), 256, 0, stream>>>(key, value, query, Akb, Avb,
                                               Aqb);

  // Q scale folds 1/sqrt(DH) and log2(e) so softmax runs on exp2 directly.
  const float qscale = 0.125f * 1.44269504088896340736f;
  qkvgemm_k<<<dim3(512, 1, 3), 256, 0, stream>>>(
      Akb, Avb, Aqb, WtK, WtV, WtQ, bk, bv, bq, Kup, Vt, Qup, qscale);

  attn_k<<<dim3(64, 16), 512, 0, stream>>>(Qup, Kup, Vt, ctx, stats);

  float* out = (float*)d_out;
  probs_k<<<dim3(16, 32, 4), 256, 0, stream>>>(Qup, Kup, stats,
                                               out + (size_t)8388608);

  outgemm_k<<<512, 256, 0, stream>>>(ctx, WtO, bo, out);
}

// Round 9
// 203.616 us; speedup vs baseline: 1.9284x; 1.0132x over previous
//
#include <hip/hip_runtime.h>
#include <hip/hip_bf16.h>
#include <stdint.h>

typedef unsigned short u16;
typedef unsigned int u32;
typedef __attribute__((ext_vector_type(8))) short bf16x8;
typedef __attribute__((ext_vector_type(4))) float f32x4;
typedef __attribute__((address_space(1))) unsigned int as1u;
typedef __attribute__((address_space(3))) unsigned int as3u;

#define DEV __device__ __forceinline__

DEV u16 f2bf(float f) {
  union { float f; unsigned u; } v; v.f = f;
  unsigned r = v.u + 0x7FFFu + ((v.u >> 16) & 1u);  // RNE
  return (u16)(r >> 16);
}

// hardware packed fp32->bf16 convert (no builtin on gfx950)
DEV u32 cvtpk(float lo, float hi) {
  u32 r;
  asm("v_cvt_pk_bf16_f32 %0, %1, %2" : "=v"(r) : "v"(lo), "v"(hi));
  return r;
}

DEV void gl_lds16(const void* g, void* l) {
  __builtin_amdgcn_global_load_lds(
      reinterpret_cast<as1u*>(reinterpret_cast<uintptr_t>(g)),
      reinterpret_cast<as3u*>(reinterpret_cast<uintptr_t>(l)), 16, 0, 0);
}

// XOR-swizzled index helpers. Tiles are [rows][64] elements.
DEV int swzh(int r, int c) { return r * 64 + (c ^ ((r & 7) << 3)); }

// XCD swizzle for 512-block GEMM grids.
DEV int xcdswz512(int bid) { return ((bid & 7) << 6) | (bid >> 3); }

// ---------------- fp32 -> bf16 streaming convert (3 tensors via z) ---------
__global__ __launch_bounds__(256) void cvt3_k(const float* __restrict__ I0,
                                              const float* __restrict__ I1,
                                              const float* __restrict__ I2,
                                              u16* __restrict__ O0,
                                              u16* __restrict__ O1,
                                              u16* __restrict__ O2) {
  const int z = blockIdx.z;
  const float* in = z == 0 ? I0 : z == 1 ? I1 : I2;
  u16* out = z == 0 ? O0 : z == 1 ? O1 : O2;
  const int idx = blockIdx.x * 256 + threadIdx.x;
#pragma unroll
  for (int j = 0; j < 8; ++j) {
    const int i = j * 262144 + idx;
    float4 x = ((const float4*)in)[i];
    uint2 p;
    p.x = cvtpk(x.x, x.y);
    p.y = cvtpk(x.z, x.w);
    ((uint2*)out)[i] = p;
  }
}

// ---------------- weight transpose+convert (all 4 weights, z-indexed) ------
__global__ __launch_bounds__(256) void wtrans4_k(
    const float* __restrict__ W0, const float* __restrict__ W1,
    const float* __restrict__ W2, const float* __restrict__ W3,
    u16* __restrict__ T0, u16* __restrict__ T1, u16* __restrict__ T2,
    u16* __restrict__ T3) {
  const int z = blockIdx.z;
  const float* W = z == 0 ? W0 : z == 1 ? W1 : z == 2 ? W2 : W3;
  u16* Wt = z == 0 ? T0 : z == 1 ? T1 : z == 2 ? T2 : T3;
  __shared__ float t[64][65];
  const int tid = threadIdx.x;
  const int n0 = blockIdx.x * 64, k0 = blockIdx.y * 64;
  const int c = tid & 63, r4 = tid >> 6;
#pragma unroll
  for (int i = 0; i < 16; ++i) {
    int r = r4 * 16 + i;
    t[r][c] = W[(size_t)(k0 + r) * 1024 + n0 + c];
  }
  __syncthreads();
#pragma unroll
  for (int i = 0; i < 16; ++i) {
    int r = r4 * 16 + i;
    Wt[(size_t)(n0 + r) * 1024 + k0 + c] = f2bf(t[c][r]);
  }
}

// ---------------- fused QKV projection GEMM, bf16 A, dbuf ------------------
__global__ __launch_bounds__(256) void qkvgemm_k(
    const u16* __restrict__ Akey, const u16* __restrict__ Aval,
    const u16* __restrict__ Aqry, const u16* __restrict__ BtK,
    const u16* __restrict__ BtV, const u16* __restrict__ BtQ,
    const float* __restrict__ bk, const float* __restrict__ bv,
    const float* __restrict__ bq, u16* __restrict__ Kup, u16* __restrict__ Vt,
    u16* __restrict__ Qup, float qscale) {
  constexpr int K = 1024;
  const int z = blockIdx.z;
  const u16* Ah = z == 0 ? Akey : z == 1 ? Aval : Aqry;
  const u16* Bt = z == 0 ? BtK : z == 1 ? BtV : BtQ;
  const float* bias = z == 0 ? bk : z == 1 ? bv : bq;
  u16* Cp = z == 0 ? Kup : z == 1 ? Vt : Qup;
  const float scale = z == 2 ? qscale : 1.0f;

  __shared__ alignas(16) char smem[65536];  // [buf][A 16K | B 16K]

  const int tid = threadIdx.x;
  const int lane = tid & 63, wid = tid >> 6;
  const int swz = xcdswz512(blockIdx.x);
  const int brow = (swz >> 3) * 128;
  const int bcol = (swz & 7) * 128;
  const int wr = (wid >> 1) * 64, wc = (wid & 1) * 64;

  f32x4 acc[4][4] = {};

  auto stage = [&](int kt, int buf) {
#pragma unroll
    for (int i = 0; i < 4; ++i) {
      int row = i * 32 + (tid >> 3);
      const int sc = ((tid & 7) ^ (row & 7)) << 3;
      gl_lds16(Ah + (size_t)(brow + row) * K + kt + sc,
               smem + buf * 32768 + i * 4096 + wid * 1024);
      gl_lds16(Bt + (size_t)(bcol + row) * K + kt + sc,
               smem + buf * 32768 + 16384 + i * 4096 + wid * 1024);
    }
  };

  stage(0, 0);
  __syncthreads();

  int cur = 0;
  for (int kt = 0; kt < K; kt += 64) {
    if (kt + 64 < K) stage(kt + 64, cur ^ 1);
    const u16* Ash = (const u16*)(smem + cur * 32768);
    const u16* Bs = (const u16*)(smem + cur * 32768 + 16384);
#pragma unroll
    for (int kk = 0; kk < 2; ++kk) {
      const int kcol = kk * 32 + (lane >> 4) * 8;
      bf16x8 a[4], bfr[4];
#pragma unroll
      for (int m = 0; m < 4; ++m)
        a[m] = *(const bf16x8*)(Ash + swzh(wr + m * 16 + (lane & 15), kcol));
#pragma unroll
      for (int n = 0; n < 4; ++n)
        bfr[n] = *(const bf16x8*)(Bs + swzh(wc + n * 16 + (lane & 15), kcol));
#pragma unroll
      for (int m = 0; m < 4; ++m)
#pragma unroll
        for (int n = 0; n < 4; ++n)
          acc[m][n] = __builtin_amdgcn_mfma_f32_16x16x32_bf16(
              a[m], bfr[n], acc[m][n], 0, 0, 0);
    }
    __syncthreads();
    cur ^= 1;
  }

  const int g = lane >> 4;
  if (z == 1) {
    // V: LDS transpose -> coalesced stores along l
    u16* T = (u16*)smem;
#pragma unroll
    for (int m = 0; m < 4; ++m) {
      const int row0 = wr + m * 16 + g * 4;  // l_local
#pragma unroll
      for (int n = 0; n < 4; ++n) {
        const int col = wc + n * 16 + (lane & 15);  // dh_local
        const float bv2 = bias[bcol + col];
        uint2 p;
        p.x = cvtpk(acc[m][n][0] + bv2, acc[m][n][1] + bv2);
        p.y = cvtpk(acc[m][n][2] + bv2, acc[m][n][3] + bv2);
        *(uint2*)((char*)T + col * 256 + ((row0 * 2) ^ ((col & 7) << 4))) = p;
      }
    }
    __syncthreads();
    const int bI = brow >> 11, l0 = brow & 2047;
#pragma unroll
    for (int i = 0; i < 8; ++i) {
      const int rr = i * 16 + (tid >> 4);
      const int xb = (tid & 15) * 16;
      uint4 v = *(uint4*)((char*)T + rr * 256 + (xb ^ ((rr & 7) << 4)));
      const int colg = bcol + rr;
      const int hh = colg >> 6, dh = colg & 63;
      *(uint4*)(&Cp[((size_t)((bI << 4) + hh) * 64 + dh) * 2048 + l0 +
                    (xb >> 1)]) = v;
    }
  } else {
#pragma unroll
    for (int m = 0; m < 4; ++m) {
      const int row0 = brow + wr + m * 16 + (g << 2);
#pragma unroll
      for (int n = 0; n < 4; ++n) {
        const int col = bcol + wc + n * 16 + (lane & 15);
        const float bv2 = bias[col];
        const int h = col >> 6, dh = col & 63;
#pragma unroll
        for (int r = 0; r < 4; ++r) {
          const int row = row0 + r;
          const float val = (acc[m][n][r] + bv2) * scale;
          const int b = row >> 11, l = row & 2047;
          Cp[((size_t)((b << 4) + h) * 2048 + l) * 64 + dh] = f2bf(val);
        }
      }
    }
  }
}

// ---------------- output GEMM: C = ctx @ Wt^T + bias (fp32 out), dbuf ------
__global__ __launch_bounds__(256) void outgemm_k(const u16* __restrict__ Ah,
                                                 const u16* __restrict__ Bt,
                                                 const float* __restrict__ bias,
                                                 float* __restrict__ Cp) {
  constexpr int K = 1024;
  __shared__ alignas(16) char smem[65536];

  const int tid = threadIdx.x;
  const int lane = tid & 63, wid = tid >> 6;
  const int swz = xcdswz512(blockIdx.x);
  const int brow = (swz >> 3) * 128;
  const int bcol = (swz & 7) * 128;
  const int wr = (wid >> 1) * 64, wc = (wid & 1) * 64;

  f32x4 acc[4][4] = {};

  auto stage = [&](int kt, int buf) {
#pragma unroll
    for (int i = 0; i < 4; ++i) {
      int row = i * 32 + (tid >> 3);
      const int sc = ((tid & 7) ^ (row & 7)) << 3;
      gl_lds16(Ah + (size_t)(brow + row) * K + kt + sc,
               smem + buf * 32768 + i * 4096 + wid * 1024);
      gl_lds16(Bt + (size_t)(bcol + row) * K + kt + sc,
               smem + buf * 32768 + 16384 + i * 4096 + wid * 1024);
    }
  };

  stage(0, 0);
  __syncthreads();

  int cur = 0;
  for (int kt = 0; kt < K; kt += 64) {
    if (kt + 64 < K) stage(kt + 64, cur ^ 1);
    const u16* Ash = (const u16*)(smem + cur * 32768);
    const u16* Bs = (const u16*)(smem + cur * 32768 + 16384);
#pragma unroll
    for (int kk = 0; kk < 2; ++kk) {
      const int kcol = kk * 32 + (lane >> 4) * 8;
      bf16x8 a[4], bfr[4];
#pragma unroll
      for (int m = 0; m < 4; ++m)
        a[m] = *(const bf16x8*)(Ash + swzh(wr + m * 16 + (lane & 15), kcol));
#pragma unroll
      for (int n = 0; n < 4; ++n)
        bfr[n] = *(const bf16x8*)(Bs + swzh(wc + n * 16 + (lane & 15), kcol));
#pragma unroll
      for (int m = 0; m < 4; ++m)
#pragma unroll
        for (int n = 0; n < 4; ++n)
          acc[m][n] = __builtin_amdgcn_mfma_f32_16x16x32_bf16(
              a[m], bfr[n], acc[m][n], 0, 0, 0);
    }
    __syncthreads();
    cur ^= 1;
  }

#pragma unroll
  for (int m = 0; m < 4; ++m) {
    const int row0 = brow + wr + m * 16 + ((lane >> 4) << 2);
#pragma unroll
    for (int n = 0; n < 4; ++n) {
      const int col = bcol + wc + n * 16 + (lane & 15);
      const float bv2 = bias[col];
#pragma unroll
      for (int r = 0; r < 4; ++r)
        Cp[(size_t)(row0 + r) * 1024 + col] = acc[m][n][r] + bv2;
    }
  }
}

// ---------------- flash attention v6: KVBLK=128, MFMA l-sum ----------------
// Q,K: bf16 [bh][l][64] (Q pre-scaled by 0.125*log2e); Vt: bf16 [bh][64][l]
// 8 waves x 16 q rows = 128-row Q tile; 128-wide KV tiles (qt+1 iters).
// K tile LDS [128 kv][64 dh]; V tile LDS [64 dh][128 kv] (256B rows).
// l-sum via mfma(P, ones) -> acc_l (same D-layout as acc_o; no shfl).
__global__ __launch_bounds__(512, 4) void attn_k(const u16* __restrict__ Q,
                                                 const u16* __restrict__ K,
                                                 const u16* __restrict__ Vt,
                                                 u16* __restrict__ ctx,
                                                 float2* __restrict__ stats) {
  const int tid = threadIdx.x, lane = tid & 63, wid = tid >> 6;
  const int bh = blockIdx.x;
  const int qt = 15 - (int)blockIdx.y;  // heavy blocks first
  const int b = bh >> 4, h = bh & 15;
  const size_t base = (size_t)bh * 2048 * 64;

  __shared__ alignas(16) u16 Ks[2][8192], Vs[2][8192], Ps[8192];

  // Q frag: row q = qt*128 + wid*16 + (lane&15), k = (lane>>4)*8
  bf16x8 qf[2];
  {
    const u16* qp = Q + base +
                    (size_t)(qt * 128 + wid * 16 + (lane & 15)) * 64 +
                    ((lane >> 4) << 3);
    qf[0] = *(const bf16x8*)(qp);
    qf[1] = *(const bf16x8*)(qp + 32);
  }
  bf16x8 ones;
#pragma unroll
  for (int i = 0; i < 8; ++i) ones[i] = (short)0x3F80;  // bf16 1.0

  // staging (512 threads): K 2 passes of 64 rows; V 2 passes of 32 rows
  const int srowK = tid >> 3;                         // 0..63
  const int scolK = ((tid & 7) ^ (srowK & 7)) << 3;   // elements
  const int srowV = tid >> 4;                         // 0..31
  const int scolV = ((tid & 15) ^ (srowV & 7)) << 3;  // elements
  auto stage = [&](int kt, int buf) {
#pragma unroll
    for (int i = 0; i < 2; ++i)
      gl_lds16(K + base + (size_t)(kt * 128 + i * 64 + srowK) * 64 + scolK,
               (char*)Ks + buf * 16384 + i * 8192 + tid * 16);
#pragma unroll
    for (int i = 0; i < 2; ++i)
      gl_lds16(Vt + base + (size_t)(i * 32 + srowV) * 2048 + kt * 128 + scolV,
               (char*)Vs + buf * 16384 + i * 8192 + tid * 16);
  };

  f32x4 acc_o[4] = {}, acc_l = {};
  float m_run = -1e30f;
  const int q = qt * 128 + wid * 16 + (lane & 15);  // this lane's softmax row
  const int g = lane >> 4;
  const int l7 = lane & 7;

  stage(0, 0);
  __syncthreads();

  int cur = 0;
  for (int kt = 0; kt <= qt; ++kt) {
    if (kt < qt) stage(kt + 1, cur ^ 1);

    // QK^T swapped: s[n2] rows kv = kt*128 + n2*16 + g*4 + r, col q
    f32x4 s[8] = {};
#pragma unroll
    for (int kk = 0; kk < 2; ++kk) {
      const int kcb = kk * 64 + g * 16;
#pragma unroll
      for (int n2 = 0; n2 < 8; ++n2) {
        const int row = n2 * 16 + (lane & 15);
        bf16x8 kf = *(const bf16x8*)((char*)Ks + cur * 16384 + row * 128 +
                                     (kcb ^ ((row & 7) << 4)));
        s[n2] = __builtin_amdgcn_mfma_f32_16x16x32_bf16(kf, qf[kk], s[n2],
                                                        0, 0, 0);
      }
    }

    if (kt == qt) {  // diagonal tile: mask kv > q
      const int kb = kt * 128 + g * 4;
#pragma unroll
      for (int n2 = 0; n2 < 8; ++n2)
#pragma unroll
        for (int r = 0; r < 4; ++r)
          if (kb + n2 * 16 + r > q) s[n2][r] = -1e30f;
    }

    // max over 32 in-lane (max3-friendly chains) + 2 shfl
    float mn0 = fmaxf(fmaxf(fmaxf(s[0][0], s[0][1]), fmaxf(s[0][2], s[0][3])),
                      fmaxf(fmaxf(s[1][0], s[1][1]), fmaxf(s[1][2], s[1][3])));
    float mn1 = fmaxf(fmaxf(fmaxf(s[2][0], s[2][1]), fmaxf(s[2][2], s[2][3])),
                      fmaxf(fmaxf(s[3][0], s[3][1]), fmaxf(s[3][2], s[3][3])));
    float mn2 = fmaxf(fmaxf(fmaxf(s[4][0], s[4][1]), fmaxf(s[4][2], s[4][3])),
                      fmaxf(fmaxf(s[5][0], s[5][1]), fmaxf(s[5][2], s[5][3])));
    float mn3 = fmaxf(fmaxf(fmaxf(s[6][0], s[6][1]), fmaxf(s[6][2], s[6][3])),
                      fmaxf(fmaxf(s[7][0], s[7][1]), fmaxf(s[7][2], s[7][3])));
    float mx = fmaxf(fmaxf(mn0, mn1), fmaxf(mn2, mn3));
    mx = fmaxf(mx, __shfl_xor(mx, 16, 64));
    mx = fmaxf(mx, __shfl_xor(mx, 32, 64));

    if (__any(mx - m_run > 8.0f)) {  // defer-max (log2 units)
      const float mn = fmaxf(m_run, mx);
      const float alpha = exp2f(m_run - mn);
      m_run = mn;
#pragma unroll
      for (int r = 0; r < 4; ++r) {
        const float ar = __shfl(alpha, (g << 2) + r, 64);
        acc_l[r] *= ar;
#pragma unroll
        for (int n = 0; n < 4; ++n) acc_o[n][r] *= ar;
      }
    }

#pragma unroll
    for (int n2 = 0; n2 < 8; ++n2)
#pragma unroll
      for (int r = 0; r < 4; ++r) s[n2][r] = exp2f(s[n2][r] - m_run);

    // PV in two 64-kv halves through the per-wave Ps slice (DS in-order)
#pragma unroll
    for (int hf = 0; hf < 2; ++hf) {
#pragma unroll
      for (int n3 = 0; n3 < 4; ++n3) {
        const int n2 = hf * 4 + n3;
        union { u32 w[2]; uint2 u; } pk;
        pk.w[0] = cvtpk(s[n2][0], s[n2][1]);
        pk.w[1] = cvtpk(s[n2][2], s[n2][3]);
        *(uint2*)((char*)Ps + wid * 2048 + (lane & 15) * 128 +
                  ((n3 * 32 + g * 8) ^ (l7 << 4))) = pk.u;
      }
#pragma unroll
      for (int kk2 = 0; kk2 < 2; ++kk2) {
        bf16x8 pf = *(const bf16x8*)((char*)Ps + wid * 2048 +
                                     (lane & 15) * 128 +
                                     ((kk2 * 64 + g * 16) ^ (l7 << 4)));
        const int kvb = hf * 128 + kk2 * 64 + g * 16;  // bytes within V row
#pragma unroll
        for (int n = 0; n < 4; ++n) {
          const int dh = n * 16 + (lane & 15);
          bf16x8 vf = *(const bf16x8*)((char*)Vs + cur * 16384 + dh * 256 +
                                       (kvb ^ ((dh & 7) << 4)));
          acc_o[n] = __builtin_amdgcn_mfma_f32_16x16x32_bf16(pf, vf, acc_o[n],
                                                             0, 0, 0);
        }
        acc_l = __builtin_amdgcn_mfma_f32_16x16x32_bf16(pf, ones, acc_l,
                                                        0, 0, 0);
      }
    }
    __syncthreads();
    cur ^= 1;
  }

  // epilogue: rows qo = qt*128 + wid*16 + g*4 + r; acc_l holds row sums
#pragma unroll
  for (int r = 0; r < 4; ++r) {
    const float linv = 1.0f / acc_l[r];
    const int qo = qt * 128 + wid * 16 + (g << 2) + r;
#pragma unroll
    for (int n = 0; n < 4; ++n) {
      const int dh = n * 16 + (lane & 15);
      ctx[((size_t)(b * 2048 + qo)) * 1024 + h * 64 + dh] =
          f2bf(acc_o[n][r] * linv);
    }
  }
  if (h == 0) {
    float mr[4];
#pragma unroll
    for (int r = 0; r < 4; ++r) mr[r] = __shfl(m_run, (g << 2) + r, 64);
    if ((lane & 15) == 0) {
#pragma unroll
      for (int r = 0; r < 4; ++r) {
        const int qo = qt * 128 + wid * 16 + (g << 2) + r;
        stats[b * 2048 + qo] = make_float2(mr[r], acc_l[r]);
      }
    }
  }
}

// ---------------- top_attn (head 0) probabilities -------------------------
__global__ __launch_bounds__(256) void probs_k(const u16* __restrict__ Q,
                                               const u16* __restrict__ K,
                                               const float2* __restrict__ stats,
                                               float* __restrict__ out) {
  const int tid = threadIdx.x, lane = tid & 63, wid = tid >> 6;
  const int kt2 = blockIdx.x, qt = blockIdx.y, b = blockIdx.z;
  const int q0 = qt * 64, c0 = kt2 * 128;
  float* ot = out + ((size_t)b * 2048 + q0) * 2048 + c0;

  if (c0 > q0 + 63) {  // whole tile masked -> zero-fill
    const float4 z = make_float4(0.f, 0.f, 0.f, 0.f);
#pragma unroll
    for (int i = 0; i < 8; ++i) {
      const int idx = i * 256 + tid;
      *(float4*)(ot + (size_t)(idx >> 5) * 2048 + ((idx & 31) << 2)) = z;
    }
    return;
  }

  __shared__ alignas(16) u16 Qs[4096], Ks2[8192];
  const size_t base = (size_t)(b * 16) * 2048 * 64;  // h = 0
#pragma unroll
  for (int i = 0; i < 2; ++i) {
    int row = i * 32 + (tid >> 3);
    gl_lds16(Q + base + (size_t)(q0 + row) * 64 + (((tid & 7) ^ (row & 7)) << 3),
             (char*)Qs + i * 4096 + wid * 1024);
  }
#pragma unroll
  for (int i = 0; i < 4; ++i) {
    int row = i * 32 + (tid >> 3);
    gl_lds16(K + base + (size_t)(c0 + row) * 64 + (((tid & 7) ^ (row & 7)) << 3),
             (char*)Ks2 + i * 4096 + wid * 1024);
  }
  __syncthreads();

  f32x4 s[8] = {};
#pragma unroll
  for (int kk = 0; kk < 2; ++kk) {
    const int kc = kk * 32 + (lane >> 4) * 8;
    bf16x8 aq = *(const bf16x8*)(Qs + swzh(wid * 16 + (lane & 15), kc));
#pragma unroll
    for (int n = 0; n < 8; ++n) {
      bf16x8 bk = *(const bf16x8*)(Ks2 + swzh(n * 16 + (lane & 15), kc));
      s[n] = __builtin_amdgcn_mfma_f32_16x16x32_bf16(aq, bk, s[n], 0, 0, 0);
    }
  }

#pragma unroll
  for (int r = 0; r < 4; ++r) {
    const int q = q0 + wid * 16 + ((lane >> 4) << 2) + r;
    const float2 st = stats[b * 2048 + q];
    const float rl = 1.0f / st.y;
#pragma unroll
    for (int n = 0; n < 8; ++n) {
      const int kp = c0 + n * 16 + (lane & 15);
      out[((size_t)b * 2048 + q) * 2048 + kp] =
          (kp <= q) ? exp2f(s[n][r] - st.x) * rl : 0.f;
    }
  }
}

extern "C" void kernel_launch(void* const* d_in, const int* in_sizes, int n_in,
                              void* d_out, int out_size, void* d_ws,
                              size_t ws_size, hipStream_t stream) {
  (void)in_sizes; (void)n_in; (void)out_size; (void)ws_size;
  const float* key = (const float*)d_in[0];
  const float* value = (const float*)d_in[1];
  const float* query = (const float*)d_in[2];
  const float* Wk = (const float*)d_in[4];
  const float* bk = (const float*)d_in[5];
  const float* Wv = (const float*)d_in[6];
  const float* bv = (const float*)d_in[7];
  const float* Wq = (const float*)d_in[8];
  const float* bq = (const float*)d_in[9];
  const float* Wo = (const float*)d_in[10];
  const float* bo = (const float*)d_in[11];

  char* ws = (char*)d_ws;  // needs ~124 MB
  u16* WtK = (u16*)(ws);
  u16* WtV = (u16*)(ws + (2u << 20));
  u16* WtQ = (u16*)(ws + (4u << 20));
  u16* WtO = (u16*)(ws + (6u << 20));
  u16* Kup = (u16*)(ws + (8u << 20));   // [b][h][l][dh] bf16
  u16* Qup = (u16*)(ws + (24u << 20));  // [b][h][l][dh] bf16
  u16* Vt  = (u16*)(ws + (40u << 20));  // [b][h][dh][l] bf16
  u16* ctx = (u16*)(ws + (56u << 20));  // [b][l][1024] bf16
  float2* stats = (float2*)(ws + (72u << 20));  // [b*2048] (m_log2, lsum)
  u16* Akb = (u16*)(ws + (76u << 20));  // bf16 key   [8192][1024]
  u16* Avb = (u16*)(ws + (92u << 20));  // bf16 value
  u16* Aqb = (u16*)(ws + (108u << 20)); // bf16 query

  wtrans4_k<<<dim3(16, 16, 4), 256, 0, stream>>>(Wk, Wv, Wq, Wo, WtK, WtV,
                                                 WtQ, WtO);
  cvt3_k<<<dim3(1024, 1, 3), 256, 0, stream>>>(key, value, query, Akb, Avb,
                                               Aqb);

  // Q scale folds 1/sqrt(DH) and log2(e) so softmax runs on exp2 directly.
  const float qscale = 0.125f * 1.44269504088896340736f;
  qkvgemm_k<<<dim3(512, 1, 3), 256, 0, stream>>>(
      Akb, Avb, Aqb, WtK, WtV, WtQ, bk, bv, bq, Kup, Vt, Qup, qscale);

  attn_k<<<dim3(64, 16), 512, 0, stream>>>(Qup, Kup, Vt, ctx, stats);

  float* out = (float*)d_out;
  probs_k<<<dim3(16, 32, 4), 256, 0, stream>>>(Qup, Kup, stats,
                                               out + (size_t)8388608);

  outgemm_k<<<512, 256, 0, stream>>>(ctx, WtO, bo, out);
}